// Round 1
// baseline (2816.116 us; speedup 1.0000x reference)
//
#include <hip/hip_runtime.h>

#define B_ 1024
#define S_ 100
#define E_ 128
#define A_ 256
#define H_ 4

#define PADQ 64   // qh rows: only broadcast/column access -> no pad needed, keep 16B aligned
#define PADK 68   // kh rows: lane-varying b128 reads, 68*4B stride -> banks l*17 mod 32, balanced
#define PADV 65   // vh rows: scalar column reads, (k*65+d)%32 = (k+d)%32 -> conflict-free

// ---------------- kernel A: SU = softmax(key @ Wu, axis=S) -> ws ----------------
__global__ __launch_bounds__(128) void unary_softmax_kernel(
    const float* __restrict__ key, const float* __restrict__ Wu, float* __restrict__ su)
{
    __shared__ float sm[S_ * H_];
    const int b = blockIdx.x;
    const int t = threadIdx.x;

    if (t < S_) {
        const float4* row = reinterpret_cast<const float4*>(key + ((size_t)b * S_ + t) * E_);
        const float4* wu4 = reinterpret_cast<const float4*>(Wu);   // row e of Wu = 4 floats (H_=4)
        float a0 = 0.f, a1 = 0.f, a2 = 0.f, a3 = 0.f;
        #pragma unroll 4
        for (int e4 = 0; e4 < E_ / 4; ++e4) {
            float4 kv = row[e4];
            float4 w0 = wu4[e4 * 4 + 0];
            float4 w1 = wu4[e4 * 4 + 1];
            float4 w2 = wu4[e4 * 4 + 2];
            float4 w3 = wu4[e4 * 4 + 3];
            a0 += kv.x * w0.x + kv.y * w1.x + kv.z * w2.x + kv.w * w3.x;
            a1 += kv.x * w0.y + kv.y * w1.y + kv.z * w2.y + kv.w * w3.y;
            a2 += kv.x * w0.z + kv.y * w1.z + kv.z * w2.z + kv.w * w3.z;
            a3 += kv.x * w0.w + kv.y * w1.w + kv.z * w2.w + kv.w * w3.w;
        }
        sm[t * 4 + 0] = a0; sm[t * 4 + 1] = a1;
        sm[t * 4 + 2] = a2; sm[t * 4 + 3] = a3;
    }
    __syncthreads();
    if (t < H_) {
        float m = -1e30f;
        for (int s = 0; s < S_; ++s) m = fmaxf(m, sm[s * 4 + t]);
        float sum = 0.f;
        for (int s = 0; s < S_; ++s) { float p = __expf(sm[s * 4 + t] - m); sm[s * 4 + t] = p; sum += p; }
        float inv = 1.f / sum;
        for (int s = 0; s < S_; ++s) sm[s * 4 + t] *= inv;
    }
    __syncthreads();
    for (int i = t; i < S_ * H_; i += 128)
        su[(size_t)b * (S_ * H_) + i] = sm[i];
}

// ---------------- kernel B: fused projections + disentangled attention ----------------
__global__ __launch_bounds__(256, 2) void fused_attn_kernel(
    const float* __restrict__ query, const float* __restrict__ key, const float* __restrict__ value,
    const float* __restrict__ Wq, const float* __restrict__ Wk, const float* __restrict__ Wv,
    const float* __restrict__ Wres, const float* __restrict__ bres,
    const float* __restrict__ su, float* __restrict__ out)
{
    __shared__ float qh[S_ * PADQ];   // 25.6 KB
    __shared__ float kh[S_ * PADK];   // 27.2 KB
    __shared__ float vh[S_ * PADV];   // 26.0 KB
    __shared__ float uwv[64];         // (softmax(unary) slice) @ v

    const int g  = blockIdx.x;        // g = h*B + b  (head-major, matches _split_heads)
    const int h  = g >> 10;
    const int b  = g & (B_ - 1);
    const int d  = threadIdx.x & 63;  // lane
    const int w  = threadIdx.x >> 6;  // wave 0..3
    const int wu = __builtin_amdgcn_readfirstlane(w);  // force SGPR for uniform row addressing
    const int col = h * 64 + d;

    // ---- pass A: q-proj + res-proj from query; res+bres written to out (same thread adds later)
    {
        float accq[25], accr[25];
        #pragma unroll
        for (int i = 0; i < 25; ++i) { accq[i] = 0.f; accr[i] = 0.f; }
        #pragma unroll 1
        for (int ec = 0; ec < 16; ++ec) {
            float wq[8], wr[8];
            #pragma unroll
            for (int j = 0; j < 8; ++j) {
                wq[j] = Wq[(ec * 8 + j) * A_ + col];
                wr[j] = Wres[(ec * 8 + j) * A_ + col];
            }
            #pragma unroll
            for (int so = 0; so < 25; ++so) {
                const int s = so * 4 + wu;
                const float* row = query + ((size_t)b * S_ + s) * E_ + ec * 8;
                float4 x0 = *reinterpret_cast<const float4*>(row);
                float4 x1 = *reinterpret_cast<const float4*>(row + 4);
                accq[so] += x0.x*wq[0] + x0.y*wq[1] + x0.z*wq[2] + x0.w*wq[3]
                          + x1.x*wq[4] + x1.y*wq[5] + x1.z*wq[6] + x1.w*wq[7];
                accr[so] += x0.x*wr[0] + x0.y*wr[1] + x0.z*wr[2] + x0.w*wr[3]
                          + x1.x*wr[4] + x1.y*wr[5] + x1.z*wr[6] + x1.w*wr[7];
            }
        }
        const float bd = bres[col];
        #pragma unroll
        for (int so = 0; so < 25; ++so) {
            const int s = so * 4 + w;
            qh[s * PADQ + d] = accq[so];
            out[((size_t)b * S_ + s) * A_ + col] = accr[so] + bd;
        }
    }

    // ---- pass B: k-proj from key
    {
        float acck[25];
        #pragma unroll
        for (int i = 0; i < 25; ++i) acck[i] = 0.f;
        #pragma unroll 1
        for (int ec = 0; ec < 16; ++ec) {
            float wk[8];
            #pragma unroll
            for (int j = 0; j < 8; ++j) wk[j] = Wk[(ec * 8 + j) * A_ + col];
            #pragma unroll
            for (int so = 0; so < 25; ++so) {
                const int s = so * 4 + wu;
                const float* row = key + ((size_t)b * S_ + s) * E_ + ec * 8;
                float4 x0 = *reinterpret_cast<const float4*>(row);
                float4 x1 = *reinterpret_cast<const float4*>(row + 4);
                acck[so] += x0.x*wk[0] + x0.y*wk[1] + x0.z*wk[2] + x0.w*wk[3]
                          + x1.x*wk[4] + x1.y*wk[5] + x1.z*wk[6] + x1.w*wk[7];
            }
        }
        #pragma unroll
        for (int so = 0; so < 25; ++so) kh[(so * 4 + w) * PADK + d] = acck[so];
    }

    // ---- pass C: v-proj from value
    {
        float accv[25];
        #pragma unroll
        for (int i = 0; i < 25; ++i) accv[i] = 0.f;
        #pragma unroll 1
        for (int ec = 0; ec < 16; ++ec) {
            float wv[8];
            #pragma unroll
            for (int j = 0; j < 8; ++j) wv[j] = Wv[(ec * 8 + j) * A_ + col];
            #pragma unroll
            for (int so = 0; so < 25; ++so) {
                const int s = so * 4 + wu;
                const float* row = value + ((size_t)b * S_ + s) * E_ + ec * 8;
                float4 x0 = *reinterpret_cast<const float4*>(row);
                float4 x1 = *reinterpret_cast<const float4*>(row + 4);
                accv[so] += x0.x*wv[0] + x0.y*wv[1] + x0.z*wv[2] + x0.w*wv[3]
                          + x1.x*wv[4] + x1.y*wv[5] + x1.z*wv[6] + x1.w*wv[7];
            }
        }
        #pragma unroll
        for (int so = 0; so < 25; ++so) vh[(so * 4 + w) * PADV + d] = accv[so];
    }

    __syncthreads();

    // ---- means (subtract over S) for q,k; uwv = SU[g,:] @ vh
    if (w == 0) {
        float m = 0.f;
        for (int s = 0; s < S_; ++s) m += qh[s * PADQ + d];
        m *= (1.f / S_);
        for (int s = 0; s < S_; ++s) qh[s * PADQ + d] -= m;
    } else if (w == 1) {
        float m = 0.f;
        for (int s = 0; s < S_; ++s) m += kh[s * PADK + d];
        m *= (1.f / S_);
        for (int s = 0; s < S_; ++s) kh[s * PADK + d] -= m;
    } else if (w == 2) {
        const float* sg = su + (size_t)g * S_;
        float acc = 0.f;
        for (int k = 0; k < S_; ++k) acc += sg[k] * vh[k * PADV + d];
        uwv[d] = acc;
    }
    __syncthreads();

    // ---- flash-style rows: wave w owns rows qi = r*4 + w
    const int krow2 = (d < 36) ? (64 + d) : d;   // safe second k-row (masked lanes re-read own row)
    #pragma unroll 1
    for (int r = 0; r < 25; ++r) {
        const int qi = r * 4 + w;
        const float4* qv = reinterpret_cast<const float4*>(qh + qi * PADQ);      // uniform -> broadcast
        const float4* k0 = reinterpret_cast<const float4*>(kh + d * PADK);
        const float4* k1 = reinterpret_cast<const float4*>(kh + krow2 * PADK);
        float z0a = 0.f, z0b = 0.f, z1a = 0.f, z1b = 0.f;
        #pragma unroll
        for (int dq = 0; dq < 16; dq += 2) {
            float4 a0 = qv[dq], a1 = qv[dq + 1];
            float4 b0 = k0[dq], b1 = k0[dq + 1];
            z0a += a0.x*b0.x + a0.y*b0.y + a0.z*b0.z + a0.w*b0.w;
            z0b += a1.x*b1.x + a1.y*b1.y + a1.z*b1.z + a1.w*b1.w;
            float4 c0 = k1[dq], c1 = k1[dq + 1];
            z1a += a0.x*c0.x + a0.y*c0.y + a0.z*c0.z + a0.w*c0.w;
            z1b += a1.x*c1.x + a1.y*c1.y + a1.z*c1.z + a1.w*c1.w;
        }
        float z0 = z0a + z0b;
        float z1 = (d < 36) ? (z1a + z1b) : -1e30f;

        float zm = fmaxf(z0, z1);
        #pragma unroll
        for (int off = 32; off > 0; off >>= 1) zm = fmaxf(zm, __shfl_xor(zm, off, 64));
        float p0 = __expf(z0 - zm);
        float p1 = (d < 36) ? __expf(z1 - zm) : 0.f;
        float ps = p0 + p1;
        #pragma unroll
        for (int off = 32; off > 0; off >>= 1) ps += __shfl_xor(ps, off, 64);
        const float inv = 1.f / ps;
        p0 *= inv; p1 *= inv;

        // PV: lane = output column d; broadcast p_k via readlane
        float a0 = uwv[d], a1 = 0.f, a2 = 0.f, a3 = 0.f;
        const int ip0 = __float_as_int(p0);
        const int ip1 = __float_as_int(p1);
        for (int k = 0; k < 64; k += 4) {
            a0 += __int_as_float(__builtin_amdgcn_readlane(ip0, k + 0)) * vh[(k + 0) * PADV + d];
            a1 += __int_as_float(__builtin_amdgcn_readlane(ip0, k + 1)) * vh[(k + 1) * PADV + d];
            a2 += __int_as_float(__builtin_amdgcn_readlane(ip0, k + 2)) * vh[(k + 2) * PADV + d];
            a3 += __int_as_float(__builtin_amdgcn_readlane(ip0, k + 3)) * vh[(k + 3) * PADV + d];
        }
        for (int k = 64; k < 100; k += 4) {
            a0 += __int_as_float(__builtin_amdgcn_readlane(ip1, k - 64)) * vh[(k + 0) * PADV + d];
            a1 += __int_as_float(__builtin_amdgcn_readlane(ip1, k - 63)) * vh[(k + 1) * PADV + d];
            a2 += __int_as_float(__builtin_amdgcn_readlane(ip1, k - 62)) * vh[(k + 2) * PADV + d];
            a3 += __int_as_float(__builtin_amdgcn_readlane(ip1, k - 61)) * vh[(k + 3) * PADV + d];
        }
        const float acc = (a0 + a1) + (a2 + a3);

        const size_t oidx = ((size_t)b * S_ + qi) * A_ + col;
        out[oidx] += acc;   // res + bres was written by this same thread in pass A
    }
}

extern "C" void kernel_launch(void* const* d_in, const int* in_sizes, int n_in,
                              void* d_out, int out_size, void* d_ws, size_t ws_size,
                              hipStream_t stream) {
    const float* query = (const float*)d_in[0];
    const float* key   = (const float*)d_in[1];
    const float* value = (const float*)d_in[2];
    const float* Wq    = (const float*)d_in[3];
    const float* Wk    = (const float*)d_in[4];
    const float* Wv    = (const float*)d_in[5];
    const float* Wu    = (const float*)d_in[6];
    const float* Wres  = (const float*)d_in[7];
    const float* bres  = (const float*)d_in[8];
    float* out = (float*)d_out;
    float* su  = (float*)d_ws;   // 1024*100*4 floats = 1.6 MB

    unary_softmax_kernel<<<B_, 128, 0, stream>>>(key, Wu, su);
    fused_attn_kernel<<<B_ * H_, 256, 0, stream>>>(query, key, value, Wq, Wk, Wv, Wres, bres, su, out);
}

// Round 2
// 383.815 us; speedup vs baseline: 7.3372x; 7.3372x over previous
//
#include <hip/hip_runtime.h>

#define B_ 1024
#define S_ 100
#define E_ 128
#define A_ 256
#define H_ 4

typedef __attribute__((ext_vector_type(4))) float f32x4;
typedef __attribute__((ext_vector_type(8))) short s16x8;
typedef unsigned short u16;
typedef unsigned int u32;

__device__ __forceinline__ u16 f2bf(float x) {
    u32 u = __builtin_bit_cast(u32, x);
    u32 r = u + 0x7FFFu + ((u >> 16) & 1u);
    return (u16)(r >> 16);
}
__device__ __forceinline__ float bf2f(u16 h) {
    u32 u = ((u32)h) << 16;
    return __builtin_bit_cast(float, u);
}
__device__ __forceinline__ f32x4 mfma16(s16x8 a, s16x8 b, f32x4 c) {
    return __builtin_amdgcn_mfma_f32_16x16x32_bf16(a, b, c, 0, 0, 0);
}

// ---------------- kernel A: SU = softmax(key @ Wu, axis=S) -> ws ----------------
__global__ __launch_bounds__(128) void unary_softmax_kernel(
    const float* __restrict__ key, const float* __restrict__ Wu, float* __restrict__ su)
{
    __shared__ float sm[S_ * H_];
    const int b = blockIdx.x;
    const int t = threadIdx.x;

    if (t < S_) {
        const float4* row = reinterpret_cast<const float4*>(key + ((size_t)b * S_ + t) * E_);
        const float4* wu4 = reinterpret_cast<const float4*>(Wu);
        float a0 = 0.f, a1 = 0.f, a2 = 0.f, a3 = 0.f;
        #pragma unroll 4
        for (int e4 = 0; e4 < E_ / 4; ++e4) {
            float4 kv = row[e4];
            float4 w0 = wu4[e4 * 4 + 0];
            float4 w1 = wu4[e4 * 4 + 1];
            float4 w2 = wu4[e4 * 4 + 2];
            float4 w3 = wu4[e4 * 4 + 3];
            a0 += kv.x * w0.x + kv.y * w1.x + kv.z * w2.x + kv.w * w3.x;
            a1 += kv.x * w0.y + kv.y * w1.y + kv.z * w2.y + kv.w * w3.y;
            a2 += kv.x * w0.z + kv.y * w1.z + kv.z * w2.z + kv.w * w3.z;
            a3 += kv.x * w0.w + kv.y * w1.w + kv.z * w2.w + kv.w * w3.w;
        }
        sm[t * 4 + 0] = a0; sm[t * 4 + 1] = a1;
        sm[t * 4 + 2] = a2; sm[t * 4 + 3] = a3;
    }
    __syncthreads();
    if (t < H_) {
        float m = -1e30f;
        for (int s = 0; s < S_; ++s) m = fmaxf(m, sm[s * 4 + t]);
        float sum = 0.f;
        for (int s = 0; s < S_; ++s) { float p = __expf(sm[s * 4 + t] - m); sm[s * 4 + t] = p; sum += p; }
        float inv = 1.f / sum;
        for (int s = 0; s < S_; ++s) sm[s * 4 + t] *= inv;
    }
    __syncthreads();
    for (int i = t; i < S_ * H_; i += 128)
        su[(size_t)b * (S_ * H_) + i] = sm[i];
}

// ---------------- kernel W: split weights into bf16 hi/lo, B-frag-friendly layout ----------------
// layout: elem (tstep, c, col, j) at ((tstep*4+c)*256+col)*8+j ; k = tstep*32 + c*8 + j
__global__ __launch_bounds__(256) void wprep_kernel(
    const float* __restrict__ Wq, const float* __restrict__ Wk,
    const float* __restrict__ Wv, const float* __restrict__ Wres,
    u16* __restrict__ wbuf)
{
    const int z = blockIdx.x;   // 0:q-hi 1:q-lo 2:k-hi 3:k-lo 4:v-hi 5:res-hi
    const float* src = (z < 2) ? Wq : (z < 4) ? Wk : (z == 4) ? Wv : Wres;
    const bool lo = (z == 1) || (z == 3);
    u16* dst = wbuf + (size_t)z * 32768;
    for (int i = threadIdx.x; i < E_ * A_; i += 256) {
        int e = i >> 8, col = i & 255;
        float x = src[i];
        u16 hi = f2bf(x);
        u16 outv = lo ? f2bf(x - bf2f(hi)) : hi;
        int ts = e >> 5, c = (e >> 3) & 3, j = e & 7;
        dst[(((ts * 4 + c) * 256 + col) << 3) + j] = outv;
    }
}

template<bool CENTER>
__device__ __forceinline__ void load_afrag(const float* rowptr, const float* xb, int koff,
                                           s16x8& ahi, s16x8& alo)
{
    float v[8];
    float4 x0 = *reinterpret_cast<const float4*>(rowptr + koff);
    float4 x1 = *reinterpret_cast<const float4*>(rowptr + koff + 4);
    v[0]=x0.x; v[1]=x0.y; v[2]=x0.z; v[3]=x0.w;
    v[4]=x1.x; v[5]=x1.y; v[6]=x1.z; v[7]=x1.w;
    if (CENTER) {
        float4 m0 = *reinterpret_cast<const float4*>(xb + koff);
        float4 m1 = *reinterpret_cast<const float4*>(xb + koff + 4);
        v[0]-=m0.x; v[1]-=m0.y; v[2]-=m0.z; v[3]-=m0.w;
        v[4]-=m1.x; v[5]-=m1.y; v[6]-=m1.z; v[7]-=m1.w;
    }
    #pragma unroll
    for (int j = 0; j < 8; ++j) {
        u16 hb = f2bf(v[j]);
        ahi[j] = (short)hb;
        alo[j] = (short)f2bf(v[j] - bf2f(hb));
    }
}

__device__ __forceinline__ s16x8 load_bfrag(const u16* wb, int t, int colbase, int lg, int lr) {
    return *reinterpret_cast<const s16x8*>(wb + ((((t * 4 + lg) * 256) + colbase + lr) << 3));
}

// ---------------- kernel B: fused split-bf16 MFMA attention ----------------
__global__ __launch_bounds__(256, 2) void fused2_kernel(
    const float* __restrict__ query, const float* __restrict__ key, const float* __restrict__ value,
    const float* __restrict__ Wres, const float* __restrict__ bres,
    const float* __restrict__ su, const u16* __restrict__ wbuf, float* __restrict__ out)
{
    __shared__ u32 smem[19712];                 // 77 KB total
    u32* qc = smem;                              // [112][68] ushort2 (hi,lo)  30464 B
    u32* kc = smem + 7616;                       // [112][68] ushort2          30464 B
    u16* vT = (u16*)(smem + 15232);              // [64][128] bf16, xor-swz    16384 B
    float* xbq  = (float*)(smem + 19328);        // col means of query (128)
    float* xbk  = xbq + 128;                     // col means of key   (128)
    float* uwvb = xbk + 128;                     // su @ v   (64)
    float* rbarb = uwvb + 64;                    // xbar_q @ Wres slice (64)
    u16* pl = (u16*)smem;                        // P bf16 [112][136], aliases qc

    const int bid = blockIdx.x;
    const int b = bid >> 2, h = bid & 3;
    const int g = h * B_ + b;                    // head-major pair-batch index
    const int tid = threadIdx.x;
    const int l = tid & 63, w = tid >> 6;
    const int lr = l & 15, lg = l >> 4;
    const int colb = h * 64;

    const float* Xq = query + (size_t)b * (S_ * E_);
    const float* Xk = key   + (size_t)b * (S_ * E_);
    const float* Xv = value + (size_t)b * (S_ * E_);

    // ---- phase 0: column means + vT tail rows (k=112..127) zero
    if (tid < 128) {
        float s = 0.f;
        for (int r = 0; r < S_; ++r) s += Xq[r * E_ + tid];
        xbq[tid] = s * (1.f / S_);
    } else {
        int t2 = tid - 128;
        float s = 0.f;
        for (int r = 0; r < S_; ++r) s += Xk[r * E_ + t2];
        xbk[t2] = s * (1.f / S_);
    }
    #pragma unroll
    for (int i = 0; i < 4; ++i) {
        int q = tid * 4 + i;                     // 0..1023
        int d = q & 63, k = 112 + (q >> 6);
        vT[d * 128 + (((k >> 3) ^ (d & 7)) << 3) + (k & 7)] = 0;
    }
    __syncthreads();                             // B0

    const int nm = (w < 3) ? 2 : 1;              // wave 3 owns only m-tile 3
    const int mt[2] = { w, w + 4 };
    const f32x4 Z4 = { 0.f, 0.f, 0.f, 0.f };

    const u16* wqh = wbuf;
    const u16* wql = wbuf + 32768;
    const u16* wkh = wbuf + 65536;
    const u16* wkl = wbuf + 98304;
    const u16* wvh = wbuf + 131072;
    const u16* wrh = wbuf + 163840;

    s16x8 ah[2][4], al[2][4];
    f32x4 ra[2][4];                              // residual projection acc (lives to epilogue)
    #pragma unroll
    for (int im = 0; im < 2; ++im)
        #pragma unroll
        for (int n = 0; n < 4; ++n) ra[im][n] = Z4;

    // ---- q-proj (centered, 3-term) + res-proj (1-term), A = centered query
    #pragma unroll
    for (int im = 0; im < 2; ++im) if (im < nm)
        #pragma unroll
        for (int t = 0; t < 4; ++t) {
            int row = mt[im] * 16 + lr; if (row > 99) row = 99;
            load_afrag<true>(Xq + row * E_, xbq, t * 32 + lg * 8, ah[im][t], al[im][t]);
        }
    {
        f32x4 qa[2][4];
        #pragma unroll
        for (int im = 0; im < 2; ++im)
            #pragma unroll
            for (int n = 0; n < 4; ++n) qa[im][n] = Z4;
        #pragma unroll
        for (int n = 0; n < 4; ++n)
            #pragma unroll
            for (int t = 0; t < 4; ++t) {
                s16x8 bh = load_bfrag(wqh, t, colb + n * 16, lg, lr);
                s16x8 bl = load_bfrag(wql, t, colb + n * 16, lg, lr);
                s16x8 br = load_bfrag(wrh, t, colb + n * 16, lg, lr);
                #pragma unroll
                for (int im = 0; im < 2; ++im) if (im < nm) {
                    qa[im][n] = mfma16(ah[im][t], bh, qa[im][n]);
                    qa[im][n] = mfma16(ah[im][t], bl, qa[im][n]);
                    qa[im][n] = mfma16(al[im][t], bh, qa[im][n]);
                    ra[im][n] = mfma16(ah[im][t], br, ra[im][n]);
                }
            }
        #pragma unroll
        for (int im = 0; im < 2; ++im) if (im < nm)
            #pragma unroll
            for (int n = 0; n < 4; ++n)
                #pragma unroll
                for (int j = 0; j < 4; ++j) {
                    int row = mt[im] * 16 + lg * 4 + j;
                    float v = qa[im][n][j];
                    u16 hb = f2bf(v);
                    u16 lb = f2bf(v - bf2f(hb));
                    qc[row * 68 + n * 16 + lr] = (u32)hb | ((u32)lb << 16);
                }
    }

    // ---- k-proj (centered, 3-term)
    #pragma unroll
    for (int im = 0; im < 2; ++im) if (im < nm)
        #pragma unroll
        for (int t = 0; t < 4; ++t) {
            int row = mt[im] * 16 + lr; if (row > 99) row = 99;
            load_afrag<true>(Xk + row * E_, xbk, t * 32 + lg * 8, ah[im][t], al[im][t]);
        }
    {
        f32x4 ka[2][4];
        #pragma unroll
        for (int im = 0; im < 2; ++im)
            #pragma unroll
            for (int n = 0; n < 4; ++n) ka[im][n] = Z4;
        #pragma unroll
        for (int n = 0; n < 4; ++n)
            #pragma unroll
            for (int t = 0; t < 4; ++t) {
                s16x8 bh = load_bfrag(wkh, t, colb + n * 16, lg, lr);
                s16x8 bl = load_bfrag(wkl, t, colb + n * 16, lg, lr);
                #pragma unroll
                for (int im = 0; im < 2; ++im) if (im < nm) {
                    ka[im][n] = mfma16(ah[im][t], bh, ka[im][n]);
                    ka[im][n] = mfma16(ah[im][t], bl, ka[im][n]);
                    ka[im][n] = mfma16(al[im][t], bh, ka[im][n]);
                }
            }
        #pragma unroll
        for (int im = 0; im < 2; ++im) if (im < nm)
            #pragma unroll
            for (int n = 0; n < 4; ++n)
                #pragma unroll
                for (int j = 0; j < 4; ++j) {
                    int row = mt[im] * 16 + lg * 4 + j;
                    float v = ka[im][n][j];
                    u16 hb = f2bf(v);
                    u16 lb = f2bf(v - bf2f(hb));
                    kc[row * 68 + n * 16 + lr] = (u32)hb | ((u32)lb << 16);
                }
    }

    // ---- v-proj (uncentered, 1-term) -> vT (transposed, swizzled)
    #pragma unroll
    for (int im = 0; im < 2; ++im) if (im < nm)
        #pragma unroll
        for (int t = 0; t < 4; ++t) {
            int row = mt[im] * 16 + lr; if (row > 99) row = 99;
            load_afrag<false>(Xv + row * E_, xbq, t * 32 + lg * 8, ah[im][t], al[im][t]);
        }
    {
        f32x4 va[2][4];
        #pragma unroll
        for (int im = 0; im < 2; ++im)
            #pragma unroll
            for (int n = 0; n < 4; ++n) va[im][n] = Z4;
        #pragma unroll
        for (int n = 0; n < 4; ++n)
            #pragma unroll
            for (int t = 0; t < 4; ++t) {
                s16x8 bh = load_bfrag(wvh, t, colb + n * 16, lg, lr);
                #pragma unroll
                for (int im = 0; im < 2; ++im) if (im < nm)
                    va[im][n] = mfma16(ah[im][t], bh, va[im][n]);
            }
        #pragma unroll
        for (int im = 0; im < 2; ++im) if (im < nm)
            #pragma unroll
            for (int n = 0; n < 4; ++n)
                #pragma unroll
                for (int j = 0; j < 4; ++j) {
                    int r = mt[im] * 16 + lg * 4 + j;
                    int d = n * 16 + lr;
                    vT[d * 128 + (((r >> 3) ^ (d & 7)) << 3) + (r & 7)] = f2bf(va[im][n][j]);
                }
    }
    __syncthreads();                             // B1: projections in LDS

    // ---- pair = qc @ kc^T (3-term split), logits in registers
    s16x8 qh_[2][2], ql_[2][2];
    #pragma unroll
    for (int im = 0; im < 2; ++im) if (im < nm)
        #pragma unroll
        for (int t = 0; t < 2; ++t) {
            int base = (mt[im] * 16 + lr) * 68 + t * 32 + lg * 8;
            uint4 u0 = *reinterpret_cast<const uint4*>(qc + base);
            uint4 u1 = *reinterpret_cast<const uint4*>(qc + base + 4);
            u32 uu[8] = { u0.x, u0.y, u0.z, u0.w, u1.x, u1.y, u1.z, u1.w };
            s16x8 hi, lo;
            #pragma unroll
            for (int j = 0; j < 8; ++j) { hi[j] = (short)(uu[j] & 0xFFFFu); lo[j] = (short)(uu[j] >> 16); }
            qh_[im][t] = hi; ql_[im][t] = lo;
        }
    f32x4 z[2][7];
    #pragma unroll
    for (int im = 0; im < 2; ++im)
        #pragma unroll
        for (int n = 0; n < 7; ++n) z[im][n] = Z4;
    #pragma unroll
    for (int n = 0; n < 7; ++n)
        #pragma unroll
        for (int t = 0; t < 2; ++t) {
            int base = (n * 16 + lr) * 68 + t * 32 + lg * 8;
            uint4 u0 = *reinterpret_cast<const uint4*>(kc + base);
            uint4 u1 = *reinterpret_cast<const uint4*>(kc + base + 4);
            u32 uu[8] = { u0.x, u0.y, u0.z, u0.w, u1.x, u1.y, u1.z, u1.w };
            s16x8 bh, bl;
            #pragma unroll
            for (int j = 0; j < 8; ++j) { bh[j] = (short)(uu[j] & 0xFFFFu); bl[j] = (short)(uu[j] >> 16); }
            #pragma unroll
            for (int im = 0; im < 2; ++im) if (im < nm) {
                z[im][n] = mfma16(qh_[im][t], bh, z[im][n]);
                z[im][n] = mfma16(qh_[im][t], bl, z[im][n]);
                z[im][n] = mfma16(ql_[im][t], bh, z[im][n]);
            }
        }

    // ---- wave 3 extras during pair phase: uwv = su[g]@v ; rbar = xbar_q @ Wres
    if (w == 3) {
        const float* sg = su + (size_t)g * S_;
        float acc = 0.f;
        for (int k8 = 0; k8 < 13; ++k8) {
            s16x8 vv = *reinterpret_cast<const s16x8*>(vT + l * 128 + ((k8 ^ (l & 7)) << 3));
            #pragma unroll
            for (int j = 0; j < 8; ++j) {
                int k = k8 * 8 + j;
                float s = (k < S_) ? sg[k] : 0.f;
                acc += s * bf2f((u16)vv[j]);
            }
        }
        uwvb[l] = acc;
        float rr = 0.f;
        for (int e = 0; e < E_; ++e) rr += xbq[e] * Wres[e * A_ + colb + l];
        rbarb[l] = rr;
    }

    // ---- softmax over k (rows of pair), fully in-register
    #pragma unroll
    for (int im = 0; im < 2; ++im) if (im < nm) {
        if (lr >= 4) {                            // n=6 cols 100..111 invalid
            f32x4 NEG = { -1e30f, -1e30f, -1e30f, -1e30f };
            z[im][6] = NEG;
        }
        #pragma unroll
        for (int j = 0; j < 4; ++j) {
            float m = z[im][0][j];
            #pragma unroll
            for (int n = 1; n < 7; ++n) m = fmaxf(m, z[im][n][j]);
            #pragma unroll
            for (int o = 1; o < 16; o <<= 1) m = fmaxf(m, __shfl_xor(m, o, 16));
            float s = 0.f;
            #pragma unroll
            for (int n = 0; n < 7; ++n) { float p = __expf(z[im][n][j] - m); z[im][n][j] = p; s += p; }
            #pragma unroll
            for (int o = 1; o < 16; o <<= 1) s += __shfl_xor(s, o, 16);
            float inv = 1.f / s;
            #pragma unroll
            for (int n = 0; n < 7; ++n) z[im][n][j] *= inv;
        }
    }
    __syncthreads();                              // B2: all qc/kc reads done (pl aliases qc)

    // ---- write P (bf16) to LDS; cols 112..127 zeroed
    #pragma unroll
    for (int im = 0; im < 2; ++im) if (im < nm) {
        #pragma unroll
        for (int n = 0; n < 7; ++n)
            #pragma unroll
            for (int j = 0; j < 4; ++j) {
                int row = mt[im] * 16 + lg * 4 + j;
                pl[row * 136 + n * 16 + lr] = f2bf(z[im][n][j]);
            }
        #pragma unroll
        for (int j = 0; j < 4; ++j) {
            int row = mt[im] * 16 + lg * 4 + j;
            pl[row * 136 + 112 + lr] = 0;
        }
    }
    __syncthreads();                              // B3: P + vT ready

    // ---- PV (1-term bf16) + epilogue
    s16x8 pa[2][4];
    #pragma unroll
    for (int im = 0; im < 2; ++im) if (im < nm)
        #pragma unroll
        for (int t = 0; t < 4; ++t)
            pa[im][t] = *reinterpret_cast<const s16x8*>(pl + (mt[im] * 16 + lr) * 136 + t * 32 + lg * 8);
    f32x4 pv[2][4];
    #pragma unroll
    for (int im = 0; im < 2; ++im)
        #pragma unroll
        for (int n = 0; n < 4; ++n) pv[im][n] = Z4;
    #pragma unroll
    for (int n = 0; n < 4; ++n)
        #pragma unroll
        for (int t = 0; t < 4; ++t) {
            int d = n * 16 + lr;
            s16x8 bv = *reinterpret_cast<const s16x8*>(vT + d * 128 + ((((t * 4 + lg)) ^ (d & 7)) << 3));
            #pragma unroll
            for (int im = 0; im < 2; ++im) if (im < nm)
                pv[im][n] = mfma16(pa[im][t], bv, pv[im][n]);
        }

    float bv4[4];
    #pragma unroll
    for (int n = 0; n < 4; ++n) bv4[n] = bres[colb + n * 16 + lr];
    #pragma unroll
    for (int im = 0; im < 2; ++im) if (im < nm)
        #pragma unroll
        for (int n = 0; n < 4; ++n) {
            int d = n * 16 + lr;
            float add = bv4[n] + uwvb[d] + rbarb[d];
            #pragma unroll
            for (int j = 0; j < 4; ++j) {
                int row = mt[im] * 16 + lg * 4 + j;
                if (row < S_)
                    out[((size_t)b * S_ + row) * A_ + colb + d] = ra[im][n][j] + pv[im][n][j] + add;
            }
        }
}

extern "C" void kernel_launch(void* const* d_in, const int* in_sizes, int n_in,
                              void* d_out, int out_size, void* d_ws, size_t ws_size,
                              hipStream_t stream) {
    const float* query = (const float*)d_in[0];
    const float* key   = (const float*)d_in[1];
    const float* value = (const float*)d_in[2];
    const float* Wq    = (const float*)d_in[3];
    const float* Wk    = (const float*)d_in[4];
    const float* Wv    = (const float*)d_in[5];
    const float* Wu    = (const float*)d_in[6];
    const float* Wres  = (const float*)d_in[7];
    const float* bres  = (const float*)d_in[8];
    float* out = (float*)d_out;

    float* su  = (float*)d_ws;                          // 1024*100*4 floats = 1.6384 MB
    u16*  wbuf = (u16*)((char*)d_ws + 1638400);         // 6 * 64 KB = 384 KB split weights

    wprep_kernel<<<6, 256, 0, stream>>>(Wq, Wk, Wv, Wres, wbuf);
    unary_softmax_kernel<<<B_, 128, 0, stream>>>(key, Wu, su);
    fused2_kernel<<<B_ * H_, 256, 0, stream>>>(query, key, value, Wres, bres, su, wbuf, out);
}

// Round 3
// 301.399 us; speedup vs baseline: 9.3435x; 1.2734x over previous
//
#include <hip/hip_runtime.h>

#define B_ 1024
#define S_ 100
#define E_ 128
#define A_ 256
#define H_ 4

typedef __attribute__((ext_vector_type(4))) float f32x4;
typedef __attribute__((ext_vector_type(8))) short s16x8;
typedef unsigned short u16;
typedef unsigned int u32;

__device__ __forceinline__ u16 f2bf(float x) {   // round-to-nearest-even
    u32 u = __builtin_bit_cast(u32, x);
    u32 r = u + 0x7FFFu + ((u >> 16) & 1u);
    return (u16)(r >> 16);
}
__device__ __forceinline__ float bf2f(u16 h) {
    u32 u = ((u32)h) << 16;
    return __builtin_bit_cast(float, u);
}
// truncation split: x = hi + lo exactly at the f32 level (Dekker-style, hi = top-16 bits).
// returns hi bits in top half, bf16(lo) in bottom half. ~4 VALU ops.
__device__ __forceinline__ u32 splitpack(float x) {
    u32 u = __builtin_bit_cast(u32, x);
    u32 hb = u & 0xFFFF0000u;
    float l = x - __builtin_bit_cast(float, hb);
    return hb | (__builtin_bit_cast(u32, l) >> 16);
}
__device__ __forceinline__ f32x4 mfma16(s16x8 a, s16x8 b, f32x4 c) {
    return __builtin_amdgcn_mfma_f32_16x16x32_bf16(a, b, c, 0, 0, 0);
}

// ---------------- kernel A: SU = softmax(key @ Wu, axis=S) -> ws ----------------
__global__ __launch_bounds__(128) void unary_softmax_kernel(
    const float* __restrict__ key, const float* __restrict__ Wu, float* __restrict__ su)
{
    __shared__ float sm[S_ * H_];
    const int b = blockIdx.x;
    const int t = threadIdx.x;

    if (t < S_) {
        const float4* row = reinterpret_cast<const float4*>(key + ((size_t)b * S_ + t) * E_);
        const float4* wu4 = reinterpret_cast<const float4*>(Wu);
        float a0 = 0.f, a1 = 0.f, a2 = 0.f, a3 = 0.f;
        #pragma unroll 4
        for (int e4 = 0; e4 < E_ / 4; ++e4) {
            float4 kv = row[e4];
            float4 w0 = wu4[e4 * 4 + 0];
            float4 w1 = wu4[e4 * 4 + 1];
            float4 w2 = wu4[e4 * 4 + 2];
            float4 w3 = wu4[e4 * 4 + 3];
            a0 += kv.x * w0.x + kv.y * w1.x + kv.z * w2.x + kv.w * w3.x;
            a1 += kv.x * w0.y + kv.y * w1.y + kv.z * w2.y + kv.w * w3.y;
            a2 += kv.x * w0.z + kv.y * w1.z + kv.z * w2.z + kv.w * w3.z;
            a3 += kv.x * w0.w + kv.y * w1.w + kv.z * w2.w + kv.w * w3.w;
        }
        sm[t * 4 + 0] = a0; sm[t * 4 + 1] = a1;
        sm[t * 4 + 2] = a2; sm[t * 4 + 3] = a3;
    }
    __syncthreads();
    {   // parallel softmax: 32 lanes per head column
        const int hh = t >> 5, i = t & 31;
        float m = -1e30f;
        for (int s = i; s < S_; s += 32) m = fmaxf(m, sm[s * 4 + hh]);
        #pragma unroll
        for (int o = 1; o < 32; o <<= 1) m = fmaxf(m, __shfl_xor(m, o, 32));
        float sum = 0.f;
        for (int s = i; s < S_; s += 32) sum += __expf(sm[s * 4 + hh] - m);
        #pragma unroll
        for (int o = 1; o < 32; o <<= 1) sum += __shfl_xor(sum, o, 32);
        float inv = 1.f / sum;
        for (int s = i; s < S_; s += 32) sm[s * 4 + hh] = __expf(sm[s * 4 + hh] - m) * inv;
    }
    __syncthreads();
    for (int i2 = t; i2 < S_ * H_; i2 += 128)
        su[(size_t)b * (S_ * H_) + i2] = sm[i2];
}

// ---------------- kernel W: split weights into bf16 hi/lo, B-frag-friendly layout ----------------
// layout: elem (tstep, c, col, j) at ((tstep*4+c)*256+col)*8+j ; k = tstep*32 + c*8 + j
__global__ __launch_bounds__(256) void wprep_kernel(
    const float* __restrict__ Wq, const float* __restrict__ Wk,
    const float* __restrict__ Wv, const float* __restrict__ Wres,
    u16* __restrict__ wbuf)
{
    const int z = blockIdx.x;   // 0:q-hi 1:q-lo 2:k-hi 3:k-lo 4:v-hi 5:res-hi
    const float* src = (z < 2) ? Wq : (z < 4) ? Wk : (z == 4) ? Wv : Wres;
    const bool lo = (z == 1) || (z == 3);
    u16* dst = wbuf + (size_t)z * 32768;
    for (int i = threadIdx.x; i < E_ * A_; i += 256) {
        int e = i >> 8, col = i & 255;
        float x = src[i];
        u16 hi = f2bf(x);
        u16 outv = lo ? f2bf(x - bf2f(hi)) : hi;
        int ts = e >> 5, c = (e >> 3) & 3, j = e & 7;
        dst[(((ts * 4 + c) * 256 + col) << 3) + j] = outv;
    }
}

// load raw X rows as truncation-split A-frags; msk zeroes pad rows (row >= S)
__device__ __forceinline__ void load_xfrag(const float* rowptr, int koff, float msk,
                                           s16x8& ahi, s16x8& alo)
{
    float4 x0 = *reinterpret_cast<const float4*>(rowptr + koff);
    float4 x1 = *reinterpret_cast<const float4*>(rowptr + koff + 4);
    float v[8] = { x0.x, x0.y, x0.z, x0.w, x1.x, x1.y, x1.z, x1.w };
    #pragma unroll
    for (int j = 0; j < 8; ++j) {
        float x = v[j] * msk;
        u32 u = __builtin_bit_cast(u32, x);
        u32 hb = u & 0xFFFF0000u;
        float l = x - __builtin_bit_cast(float, hb);
        ahi[j] = (short)(u >> 16);
        alo[j] = (short)(__builtin_bit_cast(u32, l) >> 16);
    }
}

__device__ __forceinline__ s16x8 load_bfrag(const u16* wb, int t, int colbase, int lg, int lr) {
    return *reinterpret_cast<const s16x8*>(wb + ((((t * 4 + lg) * 256) + colbase + lr) << 3));
}

// ---------------- kernel B: fused split-bf16 MFMA attention ----------------
__global__ __launch_bounds__(256, 2) void fused3_kernel(
    const float* __restrict__ query, const float* __restrict__ key, const float* __restrict__ value,
    const float* __restrict__ bres, const float* __restrict__ su,
    const u16* __restrict__ wbuf, float* __restrict__ out)
{
    __shared__ u32 smem[19904];                  // 79616 B -> still 2 blocks/CU
    u32* qc = smem;                              // [112][68] packed (hi,lo)
    u32* kc = smem + 7616;                       // [112][68]
    u16* vT = (u16*)(smem + 15232);              // [64][128] bf16, xor-swz
    float* qmp  = (float*)(smem + 19328);        // [4 waves][4 n][16 lr] q col-sum partials
    float* kmp  = qmp + 256;                     // same for k
    float* uwvb = kmp + 256;                     // su @ v   (64)
    u16* pl = (u16*)smem;                        // P bf16 [112][136], aliases qc

    const int bid = blockIdx.x;
    // XCD-grouped swizzle: the 4 heads of batch b land on the SAME XCD (bid%8), close in time
    const int b = ((bid >> 5) << 3) | (bid & 7);
    const int h = (bid >> 3) & 3;
    const int g = h * B_ + b;                    // head-major pair-batch index
    const int tid = threadIdx.x;
    const int l = tid & 63, w = tid >> 6;
    const int lr = l & 15, lg = l >> 4;
    const int colb = h * 64;

    const float* Xq = query + (size_t)b * (S_ * E_);
    const float* Xk = key   + (size_t)b * (S_ * E_);
    const float* Xv = value + (size_t)b * (S_ * E_);

    const u16* wqh = wbuf;
    const u16* wql = wbuf + 32768;
    const u16* wkh = wbuf + 65536;
    const u16* wkl = wbuf + 98304;
    const u16* wvh = wbuf + 131072;
    const u16* wrh = wbuf + 163840;

    const int nm = (w < 3) ? 2 : 1;              // wave 3 owns only m-tile 3
    const int mt[2] = { w, w + 4 };
    const f32x4 Z4 = { 0.f, 0.f, 0.f, 0.f };

    // vT tail cols k=112..127 zero
    #pragma unroll
    for (int i = 0; i < 4; ++i) {
        int q = tid * 4 + i;
        int d = q & 63, k = 112 + (q >> 6);
        vT[d * 128 + (((k >> 3) ^ (d & 7)) << 3) + (k & 7)] = 0;
    }

    s16x8 ah[2][4], al[2][4];
    f32x4 qa[2][4], ka[2][4], ra[2][4];
    #pragma unroll
    for (int im = 0; im < 2; ++im)
        #pragma unroll
        for (int n = 0; n < 4; ++n) { qa[im][n] = Z4; ka[im][n] = Z4; ra[im][n] = Z4; }

    // ---- P1a: q-proj (3-term) + res-proj (2-term); A = RAW query rows (pads zeroed)
    #pragma unroll
    for (int im = 0; im < 2; ++im) if (im < nm) {
        int row = mt[im] * 16 + lr;
        float msk = (row < S_) ? 1.f : 0.f;
        const float* rp = Xq + (size_t)((row < S_) ? row : 0) * E_;
        #pragma unroll
        for (int t = 0; t < 4; ++t) load_xfrag(rp, t * 32 + lg * 8, msk, ah[im][t], al[im][t]);
    }
    __builtin_amdgcn_s_setprio(1);
    #pragma unroll
    for (int n = 0; n < 4; ++n)
        #pragma unroll
        for (int t = 0; t < 4; ++t) {
            s16x8 bh = load_bfrag(wqh, t, colb + n * 16, lg, lr);
            s16x8 bl = load_bfrag(wql, t, colb + n * 16, lg, lr);
            s16x8 br = load_bfrag(wrh, t, colb + n * 16, lg, lr);
            #pragma unroll
            for (int im = 0; im < 2; ++im) if (im < nm) {
                qa[im][n] = mfma16(ah[im][t], bh, qa[im][n]);
                qa[im][n] = mfma16(ah[im][t], bl, qa[im][n]);
                qa[im][n] = mfma16(al[im][t], bh, qa[im][n]);
                ra[im][n] = mfma16(ah[im][t], br, ra[im][n]);
                ra[im][n] = mfma16(al[im][t], br, ra[im][n]);
            }
        }
    __builtin_amdgcn_s_setprio(0);
    // q column-sum partials (pad rows contribute exact 0)
    #pragma unroll
    for (int n = 0; n < 4; ++n) {
        float p = 0.f;
        #pragma unroll
        for (int im = 0; im < 2; ++im) if (im < nm)
            #pragma unroll
            for (int j = 0; j < 4; ++j) p += qa[im][n][j];
        p += __shfl_xor(p, 16, 64);
        p += __shfl_xor(p, 32, 64);
        if (lg == 0) qmp[(w * 4 + n) * 16 + lr] = p;
    }

    // ---- P1b: k-proj (3-term)
    #pragma unroll
    for (int im = 0; im < 2; ++im) if (im < nm) {
        int row = mt[im] * 16 + lr;
        float msk = (row < S_) ? 1.f : 0.f;
        const float* rp = Xk + (size_t)((row < S_) ? row : 0) * E_;
        #pragma unroll
        for (int t = 0; t < 4; ++t) load_xfrag(rp, t * 32 + lg * 8, msk, ah[im][t], al[im][t]);
    }
    __builtin_amdgcn_s_setprio(1);
    #pragma unroll
    for (int n = 0; n < 4; ++n)
        #pragma unroll
        for (int t = 0; t < 4; ++t) {
            s16x8 bh = load_bfrag(wkh, t, colb + n * 16, lg, lr);
            s16x8 bl = load_bfrag(wkl, t, colb + n * 16, lg, lr);
            #pragma unroll
            for (int im = 0; im < 2; ++im) if (im < nm) {
                ka[im][n] = mfma16(ah[im][t], bh, ka[im][n]);
                ka[im][n] = mfma16(ah[im][t], bl, ka[im][n]);
                ka[im][n] = mfma16(al[im][t], bh, ka[im][n]);
            }
        }
    __builtin_amdgcn_s_setprio(0);
    #pragma unroll
    for (int n = 0; n < 4; ++n) {
        float p = 0.f;
        #pragma unroll
        for (int im = 0; im < 2; ++im) if (im < nm)
            #pragma unroll
            for (int j = 0; j < 4; ++j) p += ka[im][n][j];
        p += __shfl_xor(p, 16, 64);
        p += __shfl_xor(p, 32, 64);
        if (lg == 0) kmp[(w * 4 + n) * 16 + lr] = p;
    }
    __syncthreads();                             // B1: mean partials visible

    // ---- P2: finish means, write centered split qc/kc
    #pragma unroll
    for (int n = 0; n < 4; ++n) {
        float qm = 0.f, km = 0.f;
        #pragma unroll
        for (int wv = 0; wv < 4; ++wv) {
            qm += qmp[(wv * 4 + n) * 16 + lr];
            km += kmp[(wv * 4 + n) * 16 + lr];
        }
        qm *= (1.f / S_); km *= (1.f / S_);
        #pragma unroll
        for (int im = 0; im < 2; ++im) if (im < nm)
            #pragma unroll
            for (int j = 0; j < 4; ++j) {
                int row = mt[im] * 16 + lg * 4 + j;
                qc[row * 68 + n * 16 + lr] = splitpack(qa[im][n][j] - qm);
                kc[row * 68 + n * 16 + lr] = splitpack(ka[im][n][j] - km);
            }
    }

    // ---- P3: v-proj (2-term) -> vT (transposed, swizzled)
    #pragma unroll
    for (int im = 0; im < 2; ++im) if (im < nm) {
        int row = mt[im] * 16 + lr;
        float msk = (row < S_) ? 1.f : 0.f;
        const float* rp = Xv + (size_t)((row < S_) ? row : 0) * E_;
        #pragma unroll
        for (int t = 0; t < 4; ++t) load_xfrag(rp, t * 32 + lg * 8, msk, ah[im][t], al[im][t]);
    }
    {
        f32x4 va[2][4];
        #pragma unroll
        for (int im = 0; im < 2; ++im)
            #pragma unroll
            for (int n = 0; n < 4; ++n) va[im][n] = Z4;
        __builtin_amdgcn_s_setprio(1);
        #pragma unroll
        for (int n = 0; n < 4; ++n)
            #pragma unroll
            for (int t = 0; t < 4; ++t) {
                s16x8 bh = load_bfrag(wvh, t, colb + n * 16, lg, lr);
                #pragma unroll
                for (int im = 0; im < 2; ++im) if (im < nm) {
                    va[im][n] = mfma16(ah[im][t], bh, va[im][n]);
                    va[im][n] = mfma16(al[im][t], bh, va[im][n]);
                }
            }
        __builtin_amdgcn_s_setprio(0);
        #pragma unroll
        for (int im = 0; im < 2; ++im) if (im < nm)
            #pragma unroll
            for (int n = 0; n < 4; ++n)
                #pragma unroll
                for (int j = 0; j < 4; ++j) {
                    int r = mt[im] * 16 + lg * 4 + j;
                    int d = n * 16 + lr;
                    vT[d * 128 + (((r >> 3) ^ (d & 7)) << 3) + (r & 7)] = f2bf(va[im][n][j]);
                }
    }
    __syncthreads();                             // B2: qc/kc/vT all visible

    // ---- pair = qc @ kc^T (3-term split), logits in registers
    s16x8 qhf[2][2], qlf[2][2];
    #pragma unroll
    for (int im = 0; im < 2; ++im) if (im < nm)
        #pragma unroll
        for (int t = 0; t < 2; ++t) {
            int base = (mt[im] * 16 + lr) * 68 + t * 32 + lg * 8;
            uint4 u0 = *reinterpret_cast<const uint4*>(qc + base);
            uint4 u1 = *reinterpret_cast<const uint4*>(qc + base + 4);
            u32 uu[8] = { u0.x, u0.y, u0.z, u0.w, u1.x, u1.y, u1.z, u1.w };
            s16x8 hi, lo;
            #pragma unroll
            for (int j = 0; j < 8; ++j) { hi[j] = (short)(uu[j] >> 16); lo[j] = (short)(uu[j] & 0xFFFFu); }
            qhf[im][t] = hi; qlf[im][t] = lo;
        }
    f32x4 z[2][7];
    #pragma unroll
    for (int im = 0; im < 2; ++im)
        #pragma unroll
        for (int n = 0; n < 7; ++n) z[im][n] = Z4;
    __builtin_amdgcn_s_setprio(1);
    #pragma unroll
    for (int n = 0; n < 7; ++n)
        #pragma unroll
        for (int t = 0; t < 2; ++t) {
            int base = (n * 16 + lr) * 68 + t * 32 + lg * 8;
            uint4 u0 = *reinterpret_cast<const uint4*>(kc + base);
            uint4 u1 = *reinterpret_cast<const uint4*>(kc + base + 4);
            u32 uu[8] = { u0.x, u0.y, u0.z, u0.w, u1.x, u1.y, u1.z, u1.w };
            s16x8 bh, bl;
            #pragma unroll
            for (int j = 0; j < 8; ++j) { bh[j] = (short)(uu[j] >> 16); bl[j] = (short)(uu[j] & 0xFFFFu); }
            #pragma unroll
            for (int im = 0; im < 2; ++im) if (im < nm) {
                z[im][n] = mfma16(qhf[im][t], bh, z[im][n]);
                z[im][n] = mfma16(qhf[im][t], bl, z[im][n]);
                z[im][n] = mfma16(qlf[im][t], bh, z[im][n]);
            }
        }
    __builtin_amdgcn_s_setprio(0);

    // ---- wave 3 extra during pair phase: uwv = su[g] @ v
    if (w == 3) {
        const float* sg = su + (size_t)g * S_;
        float acc = 0.f;
        for (int k8 = 0; k8 < 13; ++k8) {
            s16x8 vv = *reinterpret_cast<const s16x8*>(vT + l * 128 + ((k8 ^ (l & 7)) << 3));
            #pragma unroll
            for (int j = 0; j < 8; ++j) {
                int k = k8 * 8 + j;
                float s = (k < S_) ? sg[k] : 0.f;
                acc += s * bf2f((u16)vv[j]);
            }
        }
        uwvb[l] = acc;
    }

    // ---- softmax over k (rows of pair), fully in-register
    #pragma unroll
    for (int im = 0; im < 2; ++im) if (im < nm) {
        if (lr >= 4) {                            // n=6 cols 100..111 invalid
            f32x4 NEG = { -1e30f, -1e30f, -1e30f, -1e30f };
            z[im][6] = NEG;
        }
        #pragma unroll
        for (int j = 0; j < 4; ++j) {
            float m = z[im][0][j];
            #pragma unroll
            for (int n = 1; n < 7; ++n) m = fmaxf(m, z[im][n][j]);
            #pragma unroll
            for (int o = 1; o < 16; o <<= 1) m = fmaxf(m, __shfl_xor(m, o, 16));
            float s = 0.f;
            #pragma unroll
            for (int n = 0; n < 7; ++n) { float p = __expf(z[im][n][j] - m); z[im][n][j] = p; s += p; }
            #pragma unroll
            for (int o = 1; o < 16; o <<= 1) s += __shfl_xor(s, o, 16);
            float inv = 1.f / s;
            #pragma unroll
            for (int n = 0; n < 7; ++n) z[im][n][j] *= inv;
        }
    }
    __syncthreads();                              // B3: all qc/kc reads done (pl aliases qc)

    // ---- write P (bf16) to LDS; cols 112..127 zeroed
    #pragma unroll
    for (int im = 0; im < 2; ++im) if (im < nm) {
        #pragma unroll
        for (int n = 0; n < 7; ++n)
            #pragma unroll
            for (int j = 0; j < 4; ++j) {
                int row = mt[im] * 16 + lg * 4 + j;
                pl[row * 136 + n * 16 + lr] = f2bf(z[im][n][j]);
            }
        #pragma unroll
        for (int j = 0; j < 4; ++j) {
            int row = mt[im] * 16 + lg * 4 + j;
            pl[row * 136 + 112 + lr] = 0;
        }
    }
    __syncthreads();                              // B4: P + vT ready

    // ---- PV (1-term bf16) + epilogue
    s16x8 pa[2][4];
    #pragma unroll
    for (int im = 0; im < 2; ++im) if (im < nm)
        #pragma unroll
        for (int t = 0; t < 4; ++t)
            pa[im][t] = *reinterpret_cast<const s16x8*>(pl + (mt[im] * 16 + lr) * 136 + t * 32 + lg * 8);
    f32x4 pv[2][4];
    #pragma unroll
    for (int im = 0; im < 2; ++im)
        #pragma unroll
        for (int n = 0; n < 4; ++n) pv[im][n] = Z4;
    __builtin_amdgcn_s_setprio(1);
    #pragma unroll
    for (int n = 0; n < 4; ++n)
        #pragma unroll
        for (int t = 0; t < 4; ++t) {
            int d = n * 16 + lr;
            s16x8 bv = *reinterpret_cast<const s16x8*>(vT + d * 128 + ((((t * 4 + lg)) ^ (d & 7)) << 3));
            #pragma unroll
            for (int im = 0; im < 2; ++im) if (im < nm)
                pv[im][n] = mfma16(pa[im][t], bv, pv[im][n]);
        }
    __builtin_amdgcn_s_setprio(0);

    float bv4[4];
    #pragma unroll
    for (int n = 0; n < 4; ++n) bv4[n] = bres[colb + n * 16 + lr];
    #pragma unroll
    for (int im = 0; im < 2; ++im) if (im < nm)
        #pragma unroll
        for (int n = 0; n < 4; ++n) {
            int d = n * 16 + lr;
            float add = bv4[n] + uwvb[d];
            #pragma unroll
            for (int j = 0; j < 4; ++j) {
                int row = mt[im] * 16 + lg * 4 + j;
                if (row < S_)
                    out[((size_t)b * S_ + row) * A_ + colb + d] = ra[im][n][j] + pv[im][n][j] + add;
            }
        }
}

extern "C" void kernel_launch(void* const* d_in, const int* in_sizes, int n_in,
                              void* d_out, int out_size, void* d_ws, size_t ws_size,
                              hipStream_t stream) {
    const float* query = (const float*)d_in[0];
    const float* key   = (const float*)d_in[1];
    const float* value = (const float*)d_in[2];
    const float* Wq    = (const float*)d_in[3];
    const float* Wk    = (const float*)d_in[4];
    const float* Wv    = (const float*)d_in[5];
    const float* Wu    = (const float*)d_in[6];
    const float* Wres  = (const float*)d_in[7];
    const float* bres  = (const float*)d_in[8];
    float* out = (float*)d_out;

    float* su  = (float*)d_ws;                          // 1024*100*4 floats = 1.6384 MB
    u16*  wbuf = (u16*)((char*)d_ws + 1638400);         // 6 * 64 KB split weights

    wprep_kernel<<<6, 256, 0, stream>>>(Wq, Wk, Wv, Wres, wbuf);
    unary_softmax_kernel<<<B_, 128, 0, stream>>>(key, Wu, su);
    fused3_kernel<<<B_ * H_, 256, 0, stream>>>(query, key, value, bres, su, wbuf, out);
}

// Round 4
// 283.113 us; speedup vs baseline: 9.9470x; 1.0646x over previous
//
#include <hip/hip_runtime.h>

#define B_ 1024
#define S_ 100
#define E_ 128
#define A_ 256
#define H_ 4

typedef __attribute__((ext_vector_type(4))) float f32x4;
typedef __attribute__((ext_vector_type(8))) short s16x8;
typedef unsigned short u16;
typedef unsigned int u32;

__device__ __forceinline__ u16 f2bf(float x) {   // round-to-nearest-even
    u32 u = __builtin_bit_cast(u32, x);
    u32 r = u + 0x7FFFu + ((u >> 16) & 1u);
    return (u16)(r >> 16);
}
__device__ __forceinline__ float bf2f(u16 h) {
    u32 u = ((u32)h) << 16;
    return __builtin_bit_cast(float, u);
}
// truncation split: x = hi + lo exactly; hi bits in top half, bf16(lo) in bottom half
__device__ __forceinline__ u32 splitpack(float x) {
    u32 u = __builtin_bit_cast(u32, x);
    u32 hb = u & 0xFFFF0000u;
    float l = x - __builtin_bit_cast(float, hb);
    return hb | (__builtin_bit_cast(u32, l) >> 16);
}
__device__ __forceinline__ f32x4 mfma16(s16x8 a, s16x8 b, f32x4 c) {
    return __builtin_amdgcn_mfma_f32_16x16x32_bf16(a, b, c, 0, 0, 0);
}
__device__ __forceinline__ void split8(float4 a, float4 b, float msk, s16x8& hi, s16x8& lo) {
    float v[8] = { a.x, a.y, a.z, a.w, b.x, b.y, b.z, b.w };
    #pragma unroll
    for (int j = 0; j < 8; ++j) {
        float x = v[j] * msk;
        u32 u = __builtin_bit_cast(u32, x);
        u32 hb = u & 0xFFFF0000u;
        float l = x - __builtin_bit_cast(float, hb);
        hi[j] = (short)(u >> 16);
        lo[j] = (short)(__builtin_bit_cast(u32, l) >> 16);
    }
}
__device__ __forceinline__ s16x8 load_bfrag(const u16* wb, int t, int colbase, int lg, int lr) {
    return *reinterpret_cast<const s16x8*>(wb + ((((t * 4 + lg) * 256) + colbase + lr) << 3));
}

// ---------------- merged prep: blocks 0..1023 = unary softmax; 1024..1029 = weight split ----------------
__global__ __launch_bounds__(256) void prep_kernel(
    const float* __restrict__ key, const float* __restrict__ Wu,
    const float* __restrict__ Wq, const float* __restrict__ Wk,
    const float* __restrict__ Wv, const float* __restrict__ Wres,
    float* __restrict__ su, u16* __restrict__ wbuf)
{
    const int t = threadIdx.x;
    if (blockIdx.x >= 1024) {
        const int z = blockIdx.x - 1024;   // 0:q-hi 1:q-lo 2:k-hi 3:k-lo 4:v-hi 5:res-hi
        const float* src = (z < 2) ? Wq : (z < 4) ? Wk : (z == 4) ? Wv : Wres;
        const bool lo = (z == 1) || (z == 3);
        u16* dst = wbuf + (size_t)z * 32768;
        for (int i = t; i < E_ * A_; i += 256) {
            int e = i >> 8, col = i & 255;
            float x = src[i];
            u16 hi = f2bf(x);
            u16 outv = lo ? f2bf(x - bf2f(hi)) : hi;
            int ts = e >> 5, c = (e >> 3) & 3, j = e & 7;
            dst[(((ts * 4 + c) * 256 + col) << 3) + j] = outv;
        }
        return;
    }
    __shared__ float sm[S_ * H_];
    const int b = blockIdx.x;
    if (t < S_) {
        const float4* row = reinterpret_cast<const float4*>(key + ((size_t)b * S_ + t) * E_);
        const float4* wu4 = reinterpret_cast<const float4*>(Wu);
        float a0 = 0.f, a1 = 0.f, a2 = 0.f, a3 = 0.f;
        #pragma unroll 4
        for (int e4 = 0; e4 < E_ / 4; ++e4) {
            float4 kv = row[e4];
            float4 w0 = wu4[e4 * 4 + 0];
            float4 w1 = wu4[e4 * 4 + 1];
            float4 w2 = wu4[e4 * 4 + 2];
            float4 w3 = wu4[e4 * 4 + 3];
            a0 += kv.x * w0.x + kv.y * w1.x + kv.z * w2.x + kv.w * w3.x;
            a1 += kv.x * w0.y + kv.y * w1.y + kv.z * w2.y + kv.w * w3.y;
            a2 += kv.x * w0.z + kv.y * w1.z + kv.z * w2.z + kv.w * w3.z;
            a3 += kv.x * w0.w + kv.y * w1.w + kv.z * w2.w + kv.w * w3.w;
        }
        sm[t * 4 + 0] = a0; sm[t * 4 + 1] = a1;
        sm[t * 4 + 2] = a2; sm[t * 4 + 3] = a3;
    }
    __syncthreads();
    if (t < 128) {   // 32 lanes per head column
        const int hh = t >> 5, i = t & 31;
        float m = -1e30f;
        for (int s = i; s < S_; s += 32) m = fmaxf(m, sm[s * 4 + hh]);
        #pragma unroll
        for (int o = 1; o < 32; o <<= 1) m = fmaxf(m, __shfl_xor(m, o, 32));
        float sum = 0.f;
        for (int s = i; s < S_; s += 32) sum += __expf(sm[s * 4 + hh] - m);
        #pragma unroll
        for (int o = 1; o < 32; o <<= 1) sum += __shfl_xor(sum, o, 32);
        float inv = 1.f / sum;
        for (int s = i; s < S_; s += 32) sm[s * 4 + hh] = __expf(sm[s * 4 + hh] - m) * inv;
    }
    __syncthreads();
    for (int i2 = t; i2 < S_ * H_; i2 += 256)
        su[(size_t)b * (S_ * H_) + i2] = sm[i2];
}

// ---------------- fused kernel ----------------
__global__ __launch_bounds__(256, 2) void fused4_kernel(
    const float* __restrict__ query, const float* __restrict__ key, const float* __restrict__ value,
    const float* __restrict__ bres, const float* __restrict__ su,
    const u16* __restrict__ wbuf, float* __restrict__ out)
{
    __shared__ u32 smem[19872];               // 79488 B -> 2 blocks/CU
    u32* qc   = smem;                          // [112][68] packed (hi,lo)
    u32* kc   = smem + 7616;                   // [112][68]
    u16* vT   = (u16*)(smem + 15232);          // [64][128] bf16, xor-swz
    float* qmp  = (float*)(smem + 19328);      // [4][4][16] q col-sum partials
    float* rbuf = qmp + 256;                   // [112] r_j = qbar . k_j
    float* uwvb = rbuf + 112;                  // [64]
    float* subuf= uwvb + 64;                   // [112] su slice (tail zeroed)
    u16* pl = (u16*)smem;                      // P bf16 [112][136], aliases qc

    const int bid = blockIdx.x;
    // XCD-grouped swizzle: 4 heads of batch b on same XCD, close in time
    const int b = ((bid >> 5) << 3) | (bid & 7);
    const int h = (bid >> 3) & 3;
    const int g = h * B_ + b;
    const int tid = threadIdx.x;
    const int l = tid & 63, w = tid >> 6;
    const int lr = l & 15, lg = l >> 4;
    const int colb = h * 64;

    const float* Xq = query + (size_t)b * (S_ * E_);
    const float* Xk = key   + (size_t)b * (S_ * E_);
    const float* Xv = value + (size_t)b * (S_ * E_);

    const u16* wqh = wbuf;
    const u16* wql = wbuf + 32768;
    const u16* wkh = wbuf + 65536;
    const u16* wkl = wbuf + 98304;
    const u16* wvh = wbuf + 131072;
    const u16* wrh = wbuf + 163840;

    const int mt0 = w;
    const int mt1 = (w < 3) ? (w + 4) : 3;     // wave 3 duplicates tile 3 (branch-free)
    const int mt[2] = { mt0, mt1 };
    const float dupg = (w == 3) ? 0.f : 1.f;   // exclude dup tile from mean partials
    const f32x4 Z4 = { 0.f, 0.f, 0.f, 0.f };

    const int row0 = mt0 * 16 + lr, row1 = mt1 * 16 + lr;
    const float msk[2] = { (row0 < S_) ? 1.f : 0.f, (row1 < S_) ? 1.f : 0.f };
    const float* qp[2] = { Xq + (size_t)((row0 < S_) ? row0 : S_ - 1) * E_,
                           Xq + (size_t)((row1 < S_) ? row1 : S_ - 1) * E_ };
    const float* kp[2] = { Xk + (size_t)((row0 < S_) ? row0 : S_ - 1) * E_,
                           Xk + (size_t)((row1 < S_) ? row1 : S_ - 1) * E_ };
    const float* vp[2] = { Xv + (size_t)((row0 < S_) ? row0 : S_ - 1) * E_,
                           Xv + (size_t)((row1 < S_) ? row1 : S_ - 1) * E_ };

    // ---- issue q and k raw loads up front (latency hidden under q phase)
    float4 qr[2][4][2], kr[2][4][2];
    #pragma unroll
    for (int im = 0; im < 2; ++im)
        #pragma unroll
        for (int t = 0; t < 4; ++t) {
            qr[im][t][0] = *reinterpret_cast<const float4*>(qp[im] + t * 32 + lg * 8);
            qr[im][t][1] = *reinterpret_cast<const float4*>(qp[im] + t * 32 + lg * 8 + 4);
        }
    #pragma unroll
    for (int im = 0; im < 2; ++im)
        #pragma unroll
        for (int t = 0; t < 4; ++t) {
            kr[im][t][0] = *reinterpret_cast<const float4*>(kp[im] + t * 32 + lg * 8);
            kr[im][t][1] = *reinterpret_cast<const float4*>(kp[im] + t * 32 + lg * 8 + 4);
        }

    // ---- su slice -> LDS (tail zero); vT tail rows finite-zero (avoid stale NaN * 0)
    if (tid < S_) subuf[tid] = su[(size_t)g * S_ + tid];
    else if (tid < 112) subuf[tid] = 0.f;
    #pragma unroll
    for (int i = 0; i < 4; ++i) {
        int q = tid * 4 + i;
        int d = q & 63, k = 112 + (q >> 6);
        vT[d * 128 + (((k >> 3) ^ (d & 7)) << 3) + (k & 7)] = 0;
    }

    // ---- P1a: q-proj (3-term) + res-proj (2-term)
    s16x8 ah[2][4], al[2][4];
    #pragma unroll
    for (int im = 0; im < 2; ++im)
        #pragma unroll
        for (int t = 0; t < 4; ++t)
            split8(qr[im][t][0], qr[im][t][1], msk[im], ah[im][t], al[im][t]);

    f32x4 qa[2][4], ra[2][4];
    #pragma unroll
    for (int im = 0; im < 2; ++im)
        #pragma unroll
        for (int n = 0; n < 4; ++n) { qa[im][n] = Z4; ra[im][n] = Z4; }
    __builtin_amdgcn_s_setprio(1);
    #pragma unroll
    for (int n = 0; n < 4; ++n)
        #pragma unroll
        for (int t = 0; t < 4; ++t) {
            s16x8 bh = load_bfrag(wqh, t, colb + n * 16, lg, lr);
            s16x8 bl = load_bfrag(wql, t, colb + n * 16, lg, lr);
            s16x8 br = load_bfrag(wrh, t, colb + n * 16, lg, lr);
            #pragma unroll
            for (int im = 0; im < 2; ++im) {
                qa[im][n] = mfma16(ah[im][t], bh, qa[im][n]);
                qa[im][n] = mfma16(ah[im][t], bl, qa[im][n]);
                qa[im][n] = mfma16(al[im][t], bh, qa[im][n]);
                ra[im][n] = mfma16(ah[im][t], br, ra[im][n]);
                ra[im][n] = mfma16(al[im][t], br, ra[im][n]);
            }
        }
    __builtin_amdgcn_s_setprio(0);
    // qc write (uncentered) + q column-sum partials
    #pragma unroll
    for (int im = 0; im < 2; ++im)
        #pragma unroll
        for (int n = 0; n < 4; ++n)
            #pragma unroll
            for (int j = 0; j < 4; ++j)
                qc[(mt[im] * 16 + lg * 4 + j) * 68 + n * 16 + lr] = splitpack(qa[im][n][j]);
    #pragma unroll
    for (int n = 0; n < 4; ++n) {
        float p = 0.f;
        #pragma unroll
        for (int j = 0; j < 4; ++j) p += qa[0][n][j];
        float p1 = 0.f;
        #pragma unroll
        for (int j = 0; j < 4; ++j) p1 += qa[1][n][j];
        p += dupg * p1;
        p += __shfl_xor(p, 16, 64);
        p += __shfl_xor(p, 32, 64);
        if (lg == 0) qmp[(w * 4 + n) * 16 + lr] = p;
    }

    // ---- issue v raw loads, then k split + MFMA (v latency hides under k phase)
    float4 vr[2][4][2];
    #pragma unroll
    for (int im = 0; im < 2; ++im)
        #pragma unroll
        for (int t = 0; t < 4; ++t) {
            vr[im][t][0] = *reinterpret_cast<const float4*>(vp[im] + t * 32 + lg * 8);
            vr[im][t][1] = *reinterpret_cast<const float4*>(vp[im] + t * 32 + lg * 8 + 4);
        }
    #pragma unroll
    for (int im = 0; im < 2; ++im)
        #pragma unroll
        for (int t = 0; t < 4; ++t)
            split8(kr[im][t][0], kr[im][t][1], msk[im], ah[im][t], al[im][t]);

    f32x4 ka[2][4];
    #pragma unroll
    for (int im = 0; im < 2; ++im)
        #pragma unroll
        for (int n = 0; n < 4; ++n) ka[im][n] = Z4;
    __builtin_amdgcn_s_setprio(1);
    #pragma unroll
    for (int n = 0; n < 4; ++n)
        #pragma unroll
        for (int t = 0; t < 4; ++t) {
            s16x8 bh = load_bfrag(wkh, t, colb + n * 16, lg, lr);
            s16x8 bl = load_bfrag(wkl, t, colb + n * 16, lg, lr);
            #pragma unroll
            for (int im = 0; im < 2; ++im) {
                ka[im][n] = mfma16(ah[im][t], bh, ka[im][n]);
                ka[im][n] = mfma16(ah[im][t], bl, ka[im][n]);
                ka[im][n] = mfma16(al[im][t], bh, ka[im][n]);
            }
        }
    __builtin_amdgcn_s_setprio(0);
    #pragma unroll
    for (int im = 0; im < 2; ++im)
        #pragma unroll
        for (int n = 0; n < 4; ++n)
            #pragma unroll
            for (int j = 0; j < 4; ++j)
                kc[(mt[im] * 16 + lg * 4 + j) * 68 + n * 16 + lr] = splitpack(ka[im][n][j]);

    __syncthreads();                           // B1: qmp/subuf visible

    // ---- r_j = qbar . k_j  (per own k-rows, from live ka)
    {
        float qbar[4];
        #pragma unroll
        for (int n = 0; n < 4; ++n) {
            float s = 0.f;
            #pragma unroll
            for (int wv = 0; wv < 4; ++wv) s += qmp[(wv * 4 + n) * 16 + lr];
            qbar[n] = s * (1.f / S_);
        }
        #pragma unroll
        for (int im = 0; im < 2; ++im) {
            float pr[4];
            #pragma unroll
            for (int j = 0; j < 4; ++j) {
                float s = 0.f;
                #pragma unroll
                for (int n = 0; n < 4; ++n) s += qbar[n] * ka[im][n][j];
                pr[j] = s;
            }
            #pragma unroll
            for (int o = 1; o < 16; o <<= 1)
                #pragma unroll
                for (int j = 0; j < 4; ++j) pr[j] += __shfl_xor(pr[j], o, 16);
            if (lr == 0)
                #pragma unroll
                for (int j = 0; j < 4; ++j) rbuf[mt[im] * 16 + lg * 4 + j] = pr[j];
        }
    }

    // ---- P1c: v-proj (2-term) -> vT
    #pragma unroll
    for (int im = 0; im < 2; ++im)
        #pragma unroll
        for (int t = 0; t < 4; ++t)
            split8(vr[im][t][0], vr[im][t][1], msk[im], ah[im][t], al[im][t]);
    {
        f32x4 va[2][4];
        #pragma unroll
        for (int im = 0; im < 2; ++im)
            #pragma unroll
            for (int n = 0; n < 4; ++n) va[im][n] = Z4;
        __builtin_amdgcn_s_setprio(1);
        #pragma unroll
        for (int n = 0; n < 4; ++n)
            #pragma unroll
            for (int t = 0; t < 4; ++t) {
                s16x8 bh = load_bfrag(wvh, t, colb + n * 16, lg, lr);
                #pragma unroll
                for (int im = 0; im < 2; ++im) {
                    va[im][n] = mfma16(ah[im][t], bh, va[im][n]);
                    va[im][n] = mfma16(al[im][t], bh, va[im][n]);
                }
            }
        __builtin_amdgcn_s_setprio(0);
        #pragma unroll
        for (int im = 0; im < 2; ++im)
            #pragma unroll
            for (int n = 0; n < 4; ++n)
                #pragma unroll
                for (int j = 0; j < 4; ++j) {
                    int r = mt[im] * 16 + lg * 4 + j;
                    int d = n * 16 + lr;
                    vT[d * 128 + (((r >> 3) ^ (d & 7)) << 3) + (r & 7)] = f2bf(va[im][n][j]);
                }
    }
    __syncthreads();                           // B2: qc/kc/vT/rbuf all visible

    // ---- pair = q @ k^T (3-term split), logits in registers
    s16x8 qhf[2][2], qlf[2][2];
    #pragma unroll
    for (int im = 0; im < 2; ++im)
        #pragma unroll
        for (int t = 0; t < 2; ++t) {
            int base = (mt[im] * 16 + lr) * 68 + t * 32 + lg * 8;
            uint4 u0 = *reinterpret_cast<const uint4*>(qc + base);
            uint4 u1 = *reinterpret_cast<const uint4*>(qc + base + 4);
            u32 uu[8] = { u0.x, u0.y, u0.z, u0.w, u1.x, u1.y, u1.z, u1.w };
            s16x8 hi, lo;
            #pragma unroll
            for (int j = 0; j < 8; ++j) { hi[j] = (short)(uu[j] >> 16); lo[j] = (short)(uu[j] & 0xFFFFu); }
            qhf[im][t] = hi; qlf[im][t] = lo;
        }
    f32x4 z[2][7];
    #pragma unroll
    for (int im = 0; im < 2; ++im)
        #pragma unroll
        for (int n = 0; n < 7; ++n) z[im][n] = Z4;
    __builtin_amdgcn_s_setprio(1);
    #pragma unroll
    for (int n = 0; n < 7; ++n)
        #pragma unroll
        for (int t = 0; t < 2; ++t) {
            int base = (n * 16 + lr) * 68 + t * 32 + lg * 8;
            uint4 u0 = *reinterpret_cast<const uint4*>(kc + base);
            uint4 u1 = *reinterpret_cast<const uint4*>(kc + base + 4);
            u32 uu[8] = { u0.x, u0.y, u0.z, u0.w, u1.x, u1.y, u1.z, u1.w };
            s16x8 bh, bl;
            #pragma unroll
            for (int j = 0; j < 8; ++j) { bh[j] = (short)(uu[j] >> 16); bl[j] = (short)(uu[j] & 0xFFFFu); }
            #pragma unroll
            for (int im = 0; im < 2; ++im) {
                z[im][n] = mfma16(qhf[im][t], bh, z[im][n]);
                z[im][n] = mfma16(qhf[im][t], bl, z[im][n]);
                z[im][n] = mfma16(qlf[im][t], bh, z[im][n]);
            }
        }
    __builtin_amdgcn_s_setprio(0);

    // ---- uwv = su . v, spread over all waves (wave w owns d = w*16+lr; lg splits k)
    {
        const int d = w * 16 + lr;
        float acc = 0.f;
        #pragma unroll
        for (int c = 0; c < 3; ++c) {
            int k8 = lg + c * 4;               // chunks 0..11
            s16x8 vv = *reinterpret_cast<const s16x8*>(vT + d * 128 + ((k8 ^ (d & 7)) << 3));
            #pragma unroll
            for (int j = 0; j < 8; ++j) acc += subuf[k8 * 8 + j] * bf2f((u16)vv[j]);
        }
        if (lg == 0) {                         // chunk 12 (k=96..103; subuf[100..]=0)
            s16x8 vv = *reinterpret_cast<const s16x8*>(vT + d * 128 + ((12 ^ (d & 7)) << 3));
            #pragma unroll
            for (int j = 0; j < 8; ++j) acc += subuf[96 + j] * bf2f((u16)vv[j]);
        }
        acc += __shfl_xor(acc, 16, 64);
        acc += __shfl_xor(acc, 32, 64);
        if (lg == 0) uwvb[d] = acc;
    }

    // ---- subtract r_j, mask invalid cols, softmax over k (in-register)
    #pragma unroll
    for (int im = 0; im < 2; ++im) {
        #pragma unroll
        for (int n = 0; n < 7; ++n) {
            float rr = rbuf[n * 16 + lr];
            #pragma unroll
            for (int j = 0; j < 4; ++j) z[im][n][j] -= rr;
        }
        if (lr >= 4) {                         // cols 100..111 invalid
            f32x4 NEG = { -1e30f, -1e30f, -1e30f, -1e30f };
            z[im][6] = NEG;
        }
        #pragma unroll
        for (int j = 0; j < 4; ++j) {
            float m = z[im][0][j];
            #pragma unroll
            for (int n = 1; n < 7; ++n) m = fmaxf(m, z[im][n][j]);
            #pragma unroll
            for (int o = 1; o < 16; o <<= 1) m = fmaxf(m, __shfl_xor(m, o, 16));
            float s = 0.f;
            #pragma unroll
            for (int n = 0; n < 7; ++n) { float p = __expf(z[im][n][j] - m); z[im][n][j] = p; s += p; }
            #pragma unroll
            for (int o = 1; o < 16; o <<= 1) s += __shfl_xor(s, o, 16);
            float inv = 1.f / s;
            #pragma unroll
            for (int n = 0; n < 7; ++n) z[im][n][j] *= inv;
        }
    }
    __syncthreads();                           // B3: all qc/kc reads done (pl aliases qc)

    // ---- write P (bf16); cols 112..127 zeroed
    #pragma unroll
    for (int im = 0; im < 2; ++im) {
        #pragma unroll
        for (int n = 0; n < 7; ++n)
            #pragma unroll
            for (int j = 0; j < 4; ++j) {
                int row = mt[im] * 16 + lg * 4 + j;
                pl[row * 136 + n * 16 + lr] = f2bf(z[im][n][j]);
            }
        #pragma unroll
        for (int j = 0; j < 4; ++j) {
            int row = mt[im] * 16 + lg * 4 + j;
            pl[row * 136 + 112 + lr] = 0;
        }
    }
    __syncthreads();                           // B4: P + vT ready

    // ---- PV (1-term bf16) + epilogue
    s16x8 pa[2][4];
    #pragma unroll
    for (int im = 0; im < 2; ++im)
        #pragma unroll
        for (int t = 0; t < 4; ++t)
            pa[im][t] = *reinterpret_cast<const s16x8*>(pl + (mt[im] * 16 + lr) * 136 + t * 32 + lg * 8);
    f32x4 pv[2][4];
    #pragma unroll
    for (int im = 0; im < 2; ++im)
        #pragma unroll
        for (int n = 0; n < 4; ++n) pv[im][n] = Z4;
    __builtin_amdgcn_s_setprio(1);
    #pragma unroll
    for (int n = 0; n < 4; ++n)
        #pragma unroll
        for (int t = 0; t < 4; ++t) {
            int d = n * 16 + lr;
            s16x8 bv = *reinterpret_cast<const s16x8*>(vT + d * 128 + ((((t * 4 + lg)) ^ (d & 7)) << 3));
            #pragma unroll
            for (int im = 0; im < 2; ++im)
                pv[im][n] = mfma16(pa[im][t], bv, pv[im][n]);
        }
    __builtin_amdgcn_s_setprio(0);

    float bv4[4];
    #pragma unroll
    for (int n = 0; n < 4; ++n) bv4[n] = bres[colb + n * 16 + lr];
    #pragma unroll
    for (int im = 0; im < 2; ++im)
        #pragma unroll
        for (int n = 0; n < 4; ++n) {
            int d = n * 16 + lr;
            float add = bv4[n] + uwvb[d];
            #pragma unroll
            for (int j = 0; j < 4; ++j) {
                int row = mt[im] * 16 + lg * 4 + j;
                if (row < S_)
                    out[((size_t)b * S_ + row) * A_ + colb + d] = ra[im][n][j] + pv[im][n][j] + add;
            }
        }
}

extern "C" void kernel_launch(void* const* d_in, const int* in_sizes, int n_in,
                              void* d_out, int out_size, void* d_ws, size_t ws_size,
                              hipStream_t stream) {
    const float* query = (const float*)d_in[0];
    const float* key   = (const float*)d_in[1];
    const float* value = (const float*)d_in[2];
    const float* Wq    = (const float*)d_in[3];
    const float* Wk    = (const float*)d_in[4];
    const float* Wv    = (const float*)d_in[5];
    const float* Wu    = (const float*)d_in[6];
    const float* Wres  = (const float*)d_in[7];
    const float* bres  = (const float*)d_in[8];
    float* out = (float*)d_out;

    float* su  = (float*)d_ws;                          // 1.6384 MB
    u16*  wbuf = (u16*)((char*)d_ws + 1638400);         // 6 * 64 KB split weights

    prep_kernel<<<1030, 256, 0, stream>>>(key, Wu, Wq, Wk, Wv, Wres, su, wbuf);
    fused4_kernel<<<B_ * H_, 256, 0, stream>>>(query, key, value, bres, su, wbuf, out);
}

// Round 5
// 275.594 us; speedup vs baseline: 10.2183x; 1.0273x over previous
//
#include <hip/hip_runtime.h>

#define B_ 1024
#define S_ 100
#define E_ 128
#define A_ 256
#define H_ 4

typedef __attribute__((ext_vector_type(4))) float f32x4;
typedef __attribute__((ext_vector_type(8))) short s16x8;
typedef unsigned short u16;
typedef unsigned int u32;

__device__ __forceinline__ u16 f2bf(float x) {   // round-to-nearest-even
    u32 u = __builtin_bit_cast(u32, x);
    u32 r = u + 0x7FFFu + ((u >> 16) & 1u);
    return (u16)(r >> 16);
}
__device__ __forceinline__ float bf2f(u16 h) {
    u32 u = ((u32)h) << 16;
    return __builtin_bit_cast(float, u);
}
// truncation split: x = hi + lo exactly; hi bits in top half, bf16(lo) in bottom half
__device__ __forceinline__ u32 splitpack(float x) {
    u32 u = __builtin_bit_cast(u32, x);
    u32 hb = u & 0xFFFF0000u;
    float l = x - __builtin_bit_cast(float, hb);
    return hb | (__builtin_bit_cast(u32, l) >> 16);
}
__device__ __forceinline__ f32x4 mfma16(s16x8 a, s16x8 b, f32x4 c) {
    return __builtin_amdgcn_mfma_f32_16x16x32_bf16(a, b, c, 0, 0, 0);
}
__device__ __forceinline__ void split8(float4 a, float4 b, float msk, s16x8& hi, s16x8& lo) {
    float v[8] = { a.x, a.y, a.z, a.w, b.x, b.y, b.z, b.w };
    #pragma unroll
    for (int j = 0; j < 8; ++j) {
        float x = v[j] * msk;
        u32 u = __builtin_bit_cast(u32, x);
        u32 hb = u & 0xFFFF0000u;
        float l = x - __builtin_bit_cast(float, hb);
        hi[j] = (short)(u >> 16);
        lo[j] = (short)(__builtin_bit_cast(u32, l) >> 16);
    }
}
__device__ __forceinline__ s16x8 load_bfrag(const u16* wb, int t, int colbase, int lg, int lr) {
    return *reinterpret_cast<const s16x8*>(wb + ((((t * 4 + lg) * 256) + colbase + lr) << 3));
}

// ---------------- merged prep: blocks 0..1023 = unary softmax; 1024..1029 = weight split ----------------
__global__ __launch_bounds__(256) void prep_kernel(
    const float* __restrict__ key, const float* __restrict__ Wu,
    const float* __restrict__ Wq, const float* __restrict__ Wk,
    const float* __restrict__ Wv, const float* __restrict__ Wres,
    float* __restrict__ su, u16* __restrict__ wbuf)
{
    const int t = threadIdx.x;
    if (blockIdx.x >= 1024) {
        const int z = blockIdx.x - 1024;   // 0:q-hi 1:q-lo 2:k-hi 3:k-lo 4:v-hi 5:res-hi
        const float* src = (z < 2) ? Wq : (z < 4) ? Wk : (z == 4) ? Wv : Wres;
        const bool lo = (z == 1) || (z == 3);
        u16* dst = wbuf + (size_t)z * 32768;
        for (int i = t; i < E_ * A_; i += 256) {
            int e = i >> 8, col = i & 255;
            float x = src[i];
            u16 hi = f2bf(x);
            u16 outv = lo ? f2bf(x - bf2f(hi)) : hi;
            int ts = e >> 5, c = (e >> 3) & 3, j = e & 7;
            dst[(((ts * 4 + c) * 256 + col) << 3) + j] = outv;
        }
        return;
    }
    __shared__ float sm[S_ * H_];
    const int b = blockIdx.x;
    if (t < S_) {
        const float4* row = reinterpret_cast<const float4*>(key + ((size_t)b * S_ + t) * E_);
        const float4* wu4 = reinterpret_cast<const float4*>(Wu);
        float a0 = 0.f, a1 = 0.f, a2 = 0.f, a3 = 0.f;
        #pragma unroll 4
        for (int e4 = 0; e4 < E_ / 4; ++e4) {
            float4 kv = row[e4];
            float4 w0 = wu4[e4 * 4 + 0];
            float4 w1 = wu4[e4 * 4 + 1];
            float4 w2 = wu4[e4 * 4 + 2];
            float4 w3 = wu4[e4 * 4 + 3];
            a0 += kv.x * w0.x + kv.y * w1.x + kv.z * w2.x + kv.w * w3.x;
            a1 += kv.x * w0.y + kv.y * w1.y + kv.z * w2.y + kv.w * w3.y;
            a2 += kv.x * w0.z + kv.y * w1.z + kv.z * w2.z + kv.w * w3.z;
            a3 += kv.x * w0.w + kv.y * w1.w + kv.z * w2.w + kv.w * w3.w;
        }
        sm[t * 4 + 0] = a0; sm[t * 4 + 1] = a1;
        sm[t * 4 + 2] = a2; sm[t * 4 + 3] = a3;
    }
    __syncthreads();
    if (t < 128) {   // 32 lanes per head column
        const int hh = t >> 5, i = t & 31;
        float m = -1e30f;
        for (int s = i; s < S_; s += 32) m = fmaxf(m, sm[s * 4 + hh]);
        #pragma unroll
        for (int o = 1; o < 32; o <<= 1) m = fmaxf(m, __shfl_xor(m, o, 32));
        float sum = 0.f;
        for (int s = i; s < S_; s += 32) sum += __expf(sm[s * 4 + hh] - m);
        #pragma unroll
        for (int o = 1; o < 32; o <<= 1) sum += __shfl_xor(sum, o, 32);
        float inv = 1.f / sum;
        for (int s = i; s < S_; s += 32) sm[s * 4 + hh] = __expf(sm[s * 4 + hh] - m) * inv;
    }
    __syncthreads();
    for (int i2 = t; i2 < S_ * H_; i2 += 256)
        su[(size_t)b * (S_ * H_) + i2] = sm[i2];
}

// ---------------- fused kernel ----------------
__global__ __launch_bounds__(256, 2) void fused4_kernel(
    const float* __restrict__ query, const float* __restrict__ key, const float* __restrict__ value,
    const float* __restrict__ bres, const float* __restrict__ su,
    const u16* __restrict__ wbuf, float* __restrict__ out)
{
    __shared__ u32 smem[19872];               // 79488 B -> 2 blocks/CU
    u32* qc   = smem;                          // [112][68] packed (hi,lo)
    u32* kc   = smem + 7616;                   // [112][68]
    u16* vT   = (u16*)(smem + 15232);          // [64][128] bf16, xor-swz
    float* qmp  = (float*)(smem + 19328);      // [4][4][16] q col-sum partials
    float* rbuf = qmp + 256;                   // [112] r_j = qbar . k_j
    float* uwvb = rbuf + 112;                  // [64]
    float* subuf= uwvb + 64;                   // [112] su slice (tail zeroed)
    u16* pl = (u16*)smem;                      // P bf16 [112][136], aliases qc

    const int bid = blockIdx.x;
    // XCD-grouped swizzle: 4 heads of batch b on same XCD, close in time
    const int b = ((bid >> 5) << 3) | (bid & 7);
    const int h = (bid >> 3) & 3;
    const int g = h * B_ + b;
    const int tid = threadIdx.x;
    const int l = tid & 63, w = tid >> 6;
    const int lr = l & 15, lg = l >> 4;
    const int colb = h * 64;

    const float* Xq = query + (size_t)b * (S_ * E_);
    const float* Xk = key   + (size_t)b * (S_ * E_);
    const float* Xv = value + (size_t)b * (S_ * E_);

    const u16* wqh = wbuf;
    const u16* wql = wbuf + 32768;
    const u16* wkh = wbuf + 65536;
    const u16* wkl = wbuf + 98304;
    const u16* wvh = wbuf + 131072;
    const u16* wrh = wbuf + 163840;

    const int mt0 = w;
    const int mt1 = (w < 3) ? (w + 4) : 3;     // wave 3 duplicates tile 3 (branch-free)
    const int mt[2] = { mt0, mt1 };
    const float dupg = (w == 3) ? 0.f : 1.f;   // exclude dup tile from mean partials
    const f32x4 Z4 = { 0.f, 0.f, 0.f, 0.f };

    const int row0 = mt0 * 16 + lr, row1 = mt1 * 16 + lr;
    const float msk[2] = { (row0 < S_) ? 1.f : 0.f, (row1 < S_) ? 1.f : 0.f };
    const float* qp[2] = { Xq + (size_t)((row0 < S_) ? row0 : S_ - 1) * E_,
                           Xq + (size_t)((row1 < S_) ? row1 : S_ - 1) * E_ };
    const float* kp[2] = { Xk + (size_t)((row0 < S_) ? row0 : S_ - 1) * E_,
                           Xk + (size_t)((row1 < S_) ? row1 : S_ - 1) * E_ };
    const float* vp[2] = { Xv + (size_t)((row0 < S_) ? row0 : S_ - 1) * E_,
                           Xv + (size_t)((row1 < S_) ? row1 : S_ - 1) * E_ };

    // ---- issue q and k raw loads up front (latency hidden under q phase)
    float4 qr[2][4][2], kr[2][4][2];
    #pragma unroll
    for (int im = 0; im < 2; ++im)
        #pragma unroll
        for (int t = 0; t < 4; ++t) {
            qr[im][t][0] = *reinterpret_cast<const float4*>(qp[im] + t * 32 + lg * 8);
            qr[im][t][1] = *reinterpret_cast<const float4*>(qp[im] + t * 32 + lg * 8 + 4);
        }
    #pragma unroll
    for (int im = 0; im < 2; ++im)
        #pragma unroll
        for (int t = 0; t < 4; ++t) {
            kr[im][t][0] = *reinterpret_cast<const float4*>(kp[im] + t * 32 + lg * 8);
            kr[im][t][1] = *reinterpret_cast<const float4*>(kp[im] + t * 32 + lg * 8 + 4);
        }

    // ---- su slice -> LDS (tail zero); vT tail rows finite-zero (avoid stale NaN * 0)
    if (tid < S_) subuf[tid] = su[(size_t)g * S_ + tid];
    else if (tid < 112) subuf[tid] = 0.f;
    #pragma unroll
    for (int i = 0; i < 4; ++i) {
        int q = tid * 4 + i;
        int d = q & 63, k = 112 + (q >> 6);
        vT[d * 128 + (((k >> 3) ^ (d & 7)) << 3) + (k & 7)] = 0;
    }

    // ---- P1a: q-proj (3-term) + res-proj (2-term)
    s16x8 ah[2][4], al[2][4];
    #pragma unroll
    for (int im = 0; im < 2; ++im)
        #pragma unroll
        for (int t = 0; t < 4; ++t)
            split8(qr[im][t][0], qr[im][t][1], msk[im], ah[im][t], al[im][t]);

    f32x4 qa[2][4], ra[2][4];
    #pragma unroll
    for (int im = 0; im < 2; ++im)
        #pragma unroll
        for (int n = 0; n < 4; ++n) { qa[im][n] = Z4; ra[im][n] = Z4; }
    __builtin_amdgcn_s_setprio(1);
    #pragma unroll
    for (int n = 0; n < 4; ++n)
        #pragma unroll
        for (int t = 0; t < 4; ++t) {
            s16x8 bh = load_bfrag(wqh, t, colb + n * 16, lg, lr);
            s16x8 bl = load_bfrag(wql, t, colb + n * 16, lg, lr);
            s16x8 br = load_bfrag(wrh, t, colb + n * 16, lg, lr);
            #pragma unroll
            for (int im = 0; im < 2; ++im) {
                qa[im][n] = mfma16(ah[im][t], bh, qa[im][n]);
                qa[im][n] = mfma16(ah[im][t], bl, qa[im][n]);
                qa[im][n] = mfma16(al[im][t], bh, qa[im][n]);
                ra[im][n] = mfma16(ah[im][t], br, ra[im][n]);
                ra[im][n] = mfma16(al[im][t], br, ra[im][n]);
            }
        }
    __builtin_amdgcn_s_setprio(0);
    // qc write (uncentered) + q column-sum partials
    #pragma unroll
    for (int im = 0; im < 2; ++im)
        #pragma unroll
        for (int n = 0; n < 4; ++n)
            #pragma unroll
            for (int j = 0; j < 4; ++j)
                qc[(mt[im] * 16 + lg * 4 + j) * 68 + n * 16 + lr] = splitpack(qa[im][n][j]);
    #pragma unroll
    for (int n = 0; n < 4; ++n) {
        float p = 0.f;
        #pragma unroll
        for (int j = 0; j < 4; ++j) p += qa[0][n][j];
        float p1 = 0.f;
        #pragma unroll
        for (int j = 0; j < 4; ++j) p1 += qa[1][n][j];
        p += dupg * p1;
        p += __shfl_xor(p, 16, 64);
        p += __shfl_xor(p, 32, 64);
        if (lg == 0) qmp[(w * 4 + n) * 16 + lr] = p;
    }

    // ---- issue v raw loads, then k split + MFMA (v latency hides under k phase)
    float4 vr[2][4][2];
    #pragma unroll
    for (int im = 0; im < 2; ++im)
        #pragma unroll
        for (int t = 0; t < 4; ++t) {
            vr[im][t][0] = *reinterpret_cast<const float4*>(vp[im] + t * 32 + lg * 8);
            vr[im][t][1] = *reinterpret_cast<const float4*>(vp[im] + t * 32 + lg * 8 + 4);
        }
    #pragma unroll
    for (int im = 0; im < 2; ++im)
        #pragma unroll
        for (int t = 0; t < 4; ++t)
            split8(kr[im][t][0], kr[im][t][1], msk[im], ah[im][t], al[im][t]);

    f32x4 ka[2][4];
    #pragma unroll
    for (int im = 0; im < 2; ++im)
        #pragma unroll
        for (int n = 0; n < 4; ++n) ka[im][n] = Z4;
    __builtin_amdgcn_s_setprio(1);
    #pragma unroll
    for (int n = 0; n < 4; ++n)
        #pragma unroll
        for (int t = 0; t < 4; ++t) {
            s16x8 bh = load_bfrag(wkh, t, colb + n * 16, lg, lr);
            s16x8 bl = load_bfrag(wkl, t, colb + n * 16, lg, lr);
            #pragma unroll
            for (int im = 0; im < 2; ++im) {
                ka[im][n] = mfma16(ah[im][t], bh, ka[im][n]);
                ka[im][n] = mfma16(ah[im][t], bl, ka[im][n]);
                ka[im][n] = mfma16(al[im][t], bh, ka[im][n]);
            }
        }
    __builtin_amdgcn_s_setprio(0);
    #pragma unroll
    for (int im = 0; im < 2; ++im)
        #pragma unroll
        for (int n = 0; n < 4; ++n)
            #pragma unroll
            for (int j = 0; j < 4; ++j)
                kc[(mt[im] * 16 + lg * 4 + j) * 68 + n * 16 + lr] = splitpack(ka[im][n][j]);

    __syncthreads();                           // B1: qmp/subuf visible

    // ---- r_j = qbar . k_j  (per own k-rows, from live ka)
    {
        float qbar[4];
        #pragma unroll
        for (int n = 0; n < 4; ++n) {
            float s = 0.f;
            #pragma unroll
            for (int wv = 0; wv < 4; ++wv) s += qmp[(wv * 4 + n) * 16 + lr];
            qbar[n] = s * (1.f / S_);
        }
        #pragma unroll
        for (int im = 0; im < 2; ++im) {
            float pr[4];
            #pragma unroll
            for (int j = 0; j < 4; ++j) {
                float s = 0.f;
                #pragma unroll
                for (int n = 0; n < 4; ++n) s += qbar[n] * ka[im][n][j];
                pr[j] = s;
            }
            #pragma unroll
            for (int o = 1; o < 16; o <<= 1)
                #pragma unroll
                for (int j = 0; j < 4; ++j) pr[j] += __shfl_xor(pr[j], o, 16);
            if (lr == 0)
                #pragma unroll
                for (int j = 0; j < 4; ++j) rbuf[mt[im] * 16 + lg * 4 + j] = pr[j];
        }
    }

    // ---- P1c: v-proj (2-term) -> vT
    #pragma unroll
    for (int im = 0; im < 2; ++im)
        #pragma unroll
        for (int t = 0; t < 4; ++t)
            split8(vr[im][t][0], vr[im][t][1], msk[im], ah[im][t], al[im][t]);
    {
        f32x4 va[2][4];
        #pragma unroll
        for (int im = 0; im < 2; ++im)
            #pragma unroll
            for (int n = 0; n < 4; ++n) va[im][n] = Z4;
        __builtin_amdgcn_s_setprio(1);
        #pragma unroll
        for (int n = 0; n < 4; ++n)
            #pragma unroll
            for (int t = 0; t < 4; ++t) {
                s16x8 bh = load_bfrag(wvh, t, colb + n * 16, lg, lr);
                #pragma unroll
                for (int im = 0; im < 2; ++im) {
                    va[im][n] = mfma16(ah[im][t], bh, va[im][n]);
                    va[im][n] = mfma16(al[im][t], bh, va[im][n]);
                }
            }
        __builtin_amdgcn_s_setprio(0);
        #pragma unroll
        for (int im = 0; im < 2; ++im)
            #pragma unroll
            for (int n = 0; n < 4; ++n)
                #pragma unroll
                for (int j = 0; j < 4; ++j) {
                    int r = mt[im] * 16 + lg * 4 + j;
                    int d = n * 16 + lr;
                    vT[d * 128 + (((r >> 3) ^ (d & 7)) << 3) + (r & 7)] = f2bf(va[im][n][j]);
                }
    }
    __syncthreads();                           // B2: qc/kc/vT/rbuf all visible

    // ---- pair = q @ k^T (3-term split), logits in registers
    s16x8 qhf[2][2], qlf[2][2];
    #pragma unroll
    for (int im = 0; im < 2; ++im)
        #pragma unroll
        for (int t = 0; t < 2; ++t) {
            int base = (mt[im] * 16 + lr) * 68 + t * 32 + lg * 8;
            uint4 u0 = *reinterpret_cast<const uint4*>(qc + base);
            uint4 u1 = *reinterpret_cast<const uint4*>(qc + base + 4);
            u32 uu[8] = { u0.x, u0.y, u0.z, u0.w, u1.x, u1.y, u1.z, u1.w };
            s16x8 hi, lo;
            #pragma unroll
            for (int j = 0; j < 8; ++j) { hi[j] = (short)(uu[j] >> 16); lo[j] = (short)(uu[j] & 0xFFFFu); }
            qhf[im][t] = hi; qlf[im][t] = lo;
        }
    f32x4 z[2][7];
    #pragma unroll
    for (int im = 0; im < 2; ++im)
        #pragma unroll
        for (int n = 0; n < 7; ++n) z[im][n] = Z4;
    __builtin_amdgcn_s_setprio(1);
    #pragma unroll
    for (int n = 0; n < 7; ++n)
        #pragma unroll
        for (int t = 0; t < 2; ++t) {
            int base = (n * 16 + lr) * 68 + t * 32 + lg * 8;
            uint4 u0 = *reinterpret_cast<const uint4*>(kc + base);
            uint4 u1 = *reinterpret_cast<const uint4*>(kc + base + 4);
            u32 uu[8] = { u0.x, u0.y, u0.z, u0.w, u1.x, u1.y, u1.z, u1.w };
            s16x8 bh, bl;
            #pragma unroll
            for (int j = 0; j < 8; ++j) { bh[j] = (short)(uu[j] >> 16); bl[j] = (short)(uu[j] & 0xFFFFu); }
            #pragma unroll
            for (int im = 0; im < 2; ++im) {
                z[im][n] = mfma16(qhf[im][t], bh, z[im][n]);
                z[im][n] = mfma16(qhf[im][t], bl, z[im][n]);
                z[im][n] = mfma16(qlf[im][t], bh, z[im][n]);
            }
        }
    __builtin_amdgcn_s_setprio(0);

    // ---- uwv = su . v, spread over all waves (wave w owns d = w*16+lr; lg splits k)
    {
        const int d = w * 16 + lr;
        float acc = 0.f;
        #pragma unroll
        for (int c = 0; c < 3; ++c) {
            int k8 = lg + c * 4;               // chunks 0..11
            s16x8 vv = *reinterpret_cast<const s16x8*>(vT + d * 128 + ((k8 ^ (d & 7)) << 3));
            #pragma unroll
            for (int j = 0; j < 8; ++j) acc += subuf[k8 * 8 + j] * bf2f((u16)vv[j]);
        }
        if (lg == 0) {                         // chunk 12 (k=96..103; subuf[100..]=0)
            s16x8 vv = *reinterpret_cast<const s16x8*>(vT + d * 128 + ((12 ^ (d & 7)) << 3));
            #pragma unroll
            for (int j = 0; j < 8; ++j) acc += subuf[96 + j] * bf2f((u16)vv[j]);
        }
        acc += __shfl_xor(acc, 16, 64);
        acc += __shfl_xor(acc, 32, 64);
        if (lg == 0) uwvb[d] = acc;
    }

    // ---- subtract r_j, mask invalid cols, softmax over k (in-register)
    #pragma unroll
    for (int im = 0; im < 2; ++im) {
        #pragma unroll
        for (int n = 0; n < 7; ++n) {
            float rr = rbuf[n * 16 + lr];
            #pragma unroll
            for (int j = 0; j < 4; ++j) z[im][n][j] -= rr;
        }
        if (lr >= 4) {                         // cols 100..111 invalid
            f32x4 NEG = { -1e30f, -1e30f, -1e30f, -1e30f };
            z[im][6] = NEG;
        }
        #pragma unroll
        for (int j = 0; j < 4; ++j) {
            float m = z[im][0][j];
            #pragma unroll
            for (int n = 1; n < 7; ++n) m = fmaxf(m, z[im][n][j]);
            #pragma unroll
            for (int o = 1; o < 16; o <<= 1) m = fmaxf(m, __shfl_xor(m, o, 16));
            float s = 0.f;
            #pragma unroll
            for (int n = 0; n < 7; ++n) { float p = __expf(z[im][n][j] - m); z[im][n][j] = p; s += p; }
            #pragma unroll
            for (int o = 1; o < 16; o <<= 1) s += __shfl_xor(s, o, 16);
            float inv = 1.f / s;
            #pragma unroll
            for (int n = 0; n < 7; ++n) z[im][n][j] *= inv;
        }
    }
    __syncthreads();                           // B3: all qc/kc reads done (pl aliases qc)

    // ---- write P (bf16); cols 112..127 zeroed
    #pragma unroll
    for (int im = 0; im < 2; ++im) {
        #pragma unroll
        for (int n = 0; n < 7; ++n)
            #pragma unroll
            for (int j = 0; j < 4; ++j) {
                int row = mt[im] * 16 + lg * 4 + j;
                pl[row * 136 + n * 16 + lr] = f2bf(z[im][n][j]);
            }
        #pragma unroll
        for (int j = 0; j < 4; ++j) {
            int row = mt[im] * 16 + lg * 4 + j;
            pl[row * 136 + 112 + lr] = 0;
        }
    }
    __syncthreads();                           // B4: P + vT ready

    // ---- PV (1-term bf16) + epilogue
    s16x8 pa[2][4];
    #pragma unroll
    for (int im = 0; im < 2; ++im)
        #pragma unroll
        for (int t = 0; t < 4; ++t)
            pa[im][t] = *reinterpret_cast<const s16x8*>(pl + (mt[im] * 16 + lr) * 136 + t * 32 + lg * 8);
    f32x4 pv[2][4];
    #pragma unroll
    for (int im = 0; im < 2; ++im)
        #pragma unroll
        for (int n = 0; n < 4; ++n) pv[im][n] = Z4;
    __builtin_amdgcn_s_setprio(1);
    #pragma unroll
    for (int n = 0; n < 4; ++n)
        #pragma unroll
        for (int t = 0; t < 4; ++t) {
            int d = n * 16 + lr;
            s16x8 bv = *reinterpret_cast<const s16x8*>(vT + d * 128 + ((((t * 4 + lg)) ^ (d & 7)) << 3));
            #pragma unroll
            for (int im = 0; im < 2; ++im)
                pv[im][n] = mfma16(pa[im][t], bv, pv[im][n]);
        }
    __builtin_amdgcn_s_setprio(0);

    float bv4[4];
    #pragma unroll
    for (int n = 0; n < 4; ++n) bv4[n] = bres[colb + n * 16 + lr];
    #pragma unroll
    for (int im = 0; im < 2; ++im)
        #pragma unroll
        for (int n = 0; n < 4; ++n) {
            int d = n * 16 + lr;
            float add = bv4[n] + uwvb[d];
            #pragma unroll
            for (int j = 0; j < 4; ++j) {
                int row = mt[im] * 16 + lg * 4 + j;
                if (row < S_)
                    out[((size_t)b * S_ + row) * A_ + colb + d] = ra[im][n][j] + pv[im][n][j] + add;
            }
        }
}

extern "C" void kernel_launch(void* const* d_in, const int* in_sizes, int n_in,
                              void* d_out, int out_size, void* d_ws, size_t ws_size,
                              hipStream_t stream) {
    const float* query = (const float*)d_in[0];
    const float* key   = (const float*)d_in[1];
    const float* value = (const float*)d_in[2];
    const float* Wq    = (const float*)d_in[3];
    const float* Wk    = (const float*)d_in[4];
    const float* Wv    = (const float*)d_in[5];
    const float* Wu    = (const float*)d_in[6];
    const float* Wres  = (const float*)d_in[7];
    const float* bres  = (const float*)d_in[8];
    float* out = (float*)d_out;

    float* su  = (float*)d_ws;                          // 1.6384 MB
    u16*  wbuf = (u16*)((char*)d_ws + 1638400);         // 6 * 64 KB split weights

    prep_kernel<<<1030, 256, 0, stream>>>(key, Wu, Wq, Wk, Wv, Wres, su, wbuf);
    fused4_kernel<<<B_ * H_, 256, 0, stream>>>(query, key, value, bres, su, wbuf, out);
}